// Round 2
// baseline (1545.125 us; speedup 1.0000x reference)
//
#include <hip/hip_runtime.h>

#define MTOT 32768
#define KC   4096
#define DDIM 256
#define TM   64
#define TK   64
#define NTHREADS 256
#define ZELEMS (MTOT * DDIM)   // 8388608
#define XS_PITCH 260           // +4 floats pad, keeps 16B alignment

__device__ __forceinline__ float sqr_rn(float v) { return __fmul_rn(v, v); }

// numpy pairwise sum of squares, n=256 contiguous:
// split 128+128; each half: 8 accumulators stepping 8, combined
// ((r0+r1)+(r2+r3))+((r4+r5)+(r6+r7)); halves added last. All ops exact
// fp32 via __f*_rn intrinsics (no contraction, no reassociation).
__device__ __forceinline__ float np_sumsq_256(const float* p) {
  float half[2];
#pragma unroll
  for (int h = 0; h < 2; ++h) {
    const float* q = p + h * 128;
    float r[8];
#pragma unroll
    for (int j = 0; j < 8; ++j) r[j] = sqr_rn(q[j]);
#pragma unroll
    for (int i = 8; i < 128; i += 8)
#pragma unroll
      for (int j = 0; j < 8; ++j) r[j] = __fadd_rn(r[j], sqr_rn(q[i + j]));
    half[h] = __fadd_rn(__fadd_rn(__fadd_rn(r[0], r[1]), __fadd_rn(r[2], r[3])),
                        __fadd_rn(__fadd_rn(r[4], r[5]), __fadd_rn(r[6], r[7])));
  }
  return __fadd_rn(half[0], half[1]);
}

// ---------------- prep: codebook norms (np-exact) + zero accumulator ----------------
__global__ __launch_bounds__(NTHREADS) void vq_prep(const float* __restrict__ cb,
                                                    float* __restrict__ cnorm,
                                                    double* __restrict__ accum) {
  int k = blockIdx.x * NTHREADS + threadIdx.x;
  if (k == 0) accum[0] = 0.0;
  cnorm[k] = np_sumsq_256(cb + (size_t)k * DDIM);
}

// ---------------- main: distances, argmin, gather, loss partials ----------------
__global__ __launch_bounds__(NTHREADS) void vq_main(const float* __restrict__ x,
                                                    const float* __restrict__ cb,
                                                    const float* __restrict__ cnorm,
                                                    float* __restrict__ out,
                                                    double* __restrict__ accum) {
  __shared__ float xs[TM][XS_PITCH];    // 66,560 B, row-major x tile
  __shared__ float cst[DDIM][TK];       // 65,536 B, d-major (transposed) code tile
  __shared__ float ss[TM];              // np-exact ||x||^2 per row
  __shared__ int   idx_sh[TM];
  __shared__ float wred[4];

  const int t  = threadIdx.x;
  const int m0 = blockIdx.x * TM;

  // ---- stage x tile (coalesced) ----
#pragma unroll
  for (int i = 0; i < 16; ++i) {
    int fi  = t + i * NTHREADS;
    int row = fi >> 6, dc = fi & 63;
    float4 v = *reinterpret_cast<const float4*>(x + (size_t)(m0 + row) * DDIM + dc * 4);
    *reinterpret_cast<float4*>(&xs[row][dc * 4]) = v;
  }
  __syncthreads();

  // ---- np-exact S per row (one thread per row; one-time cost) ----
  if (t < TM) ss[t] = np_sumsq_256(&xs[t][0]);
  __syncthreads();

  const int tr = t >> 4, tc = t & 15;
  const int r0 = tr * 4;            // this thread's 4 rows
  const int c0 = tc * 4;            // this thread's 4 codes within tile

  float srow[4];
#pragma unroll
  for (int i = 0; i < 4; ++i) srow[i] = ss[r0 + i];

  float minv[4]; int mini[4];
#pragma unroll
  for (int i = 0; i < 4; ++i) { minv[i] = 3.4e38f; mini[i] = 0; }

  const int kk    = t & 63;         // staging: lane -> code (consecutive-bank LDS writes)
  const int dbase = t >> 6;         // staging: wave -> d-chunk group

  for (int kt = 0; kt < KC / TK; ++kt) {
    __syncthreads();                // protect cst readers from overwrite
    // ---- stage code tile transposed: cst[d][k] ----
#pragma unroll
    for (int i = 0; i < 16; ++i) {
      int dc4 = dbase + i * 4;      // 0..63
      float4 v = *reinterpret_cast<const float4*>(cb + (size_t)(kt * TK + kk) * DDIM + dc4 * 4);
      cst[dc4 * 4 + 0][kk] = v.x;
      cst[dc4 * 4 + 1][kk] = v.y;
      cst[dc4 * 4 + 2][kk] = v.z;
      cst[dc4 * 4 + 3][kk] = v.w;
    }
    __syncthreads();

    // ---- 4 rows x 4 codes register tile ----
    // Emulate np.einsum SSE loop: 4 lane accumulators (d mod 4), ascending d,
    // mul-then-add (NOT fma) so E matches numpy bit-for-bit.
    float acc[4][4][4];
#pragma unroll
    for (int i = 0; i < 4; ++i)
#pragma unroll
      for (int j = 0; j < 4; ++j)
#pragma unroll
        for (int dd = 0; dd < 4; ++dd) acc[i][j][dd] = 0.f;

#pragma unroll 2
    for (int d = 0; d < DDIM; d += 4) {
      float xa[4][4], cv[4][4];
#pragma unroll
      for (int i = 0; i < 4; ++i)
        *reinterpret_cast<float4*>(xa[i]) = *reinterpret_cast<float4*>(&xs[r0 + i][d]);
#pragma unroll
      for (int dd = 0; dd < 4; ++dd)
        *reinterpret_cast<float4*>(cv[dd]) = *reinterpret_cast<float4*>(&cst[d + dd][c0]);
#pragma unroll
      for (int dd = 0; dd < 4; ++dd)
#pragma unroll
        for (int i = 0; i < 4; ++i)
#pragma unroll
          for (int j = 0; j < 4; ++j)
            acc[i][j][dd] = __fadd_rn(acc[i][j][dd], __fmul_rn(xa[i][dd], cv[dd][j]));
    }

    // ---- fold to np's D = (S - 2E) + C with np's exact roundings ----
    float4 cn = *reinterpret_cast<const float4*>(cnorm + kt * TK + c0);
    float cna[4] = {cn.x, cn.y, cn.z, cn.w};
#pragma unroll
    for (int i = 0; i < 4; ++i) {
#pragma unroll
      for (int j = 0; j < 4; ++j) {
        // SSE horizontal combine order: (s0+s1)+(s2+s3)
        float e = __fadd_rn(__fadd_rn(acc[i][j][0], acc[i][j][1]),
                            __fadd_rn(acc[i][j][2], acc[i][j][3]));
        float s = __fadd_rn(__fsub_rn(srow[i], __fmul_rn(2.0f, e)), cna[j]);
        int  code = kt * TK + c0 + j;
        if (s < minv[i]) { minv[i] = s; mini[i] = code; }   // strict < keeps first index
      }
    }
  }

  // ---- reduce argmin across the 16 lanes sharing each row group ----
  float part = 0.f;
#pragma unroll
  for (int i = 0; i < 4; ++i) {
    float v = minv[i]; int ii = mini[i];
#pragma unroll
    for (int m = 8; m >= 1; m >>= 1) {
      float ov = __shfl_xor(v, m, 64);
      int   oi = __shfl_xor(ii, m, 64);
      if (ov < v || (ov == v && oi < ii)) { v = ov; ii = oi; }
    }
    if (tc == 0) {
      int row = r0 + i;
      idx_sh[row] = ii;
      out[(size_t)ZELEMS + 1 + m0 + row] = (float)ii;
      part += v;                    // D_min contribution to loss
    }
  }

  // ---- block loss partial -> one double atomic ----
#pragma unroll
  for (int off = 32; off >= 1; off >>= 1) part += __shfl_down(part, off, 64);
  if ((t & 63) == 0) wred[t >> 6] = part;
  __syncthreads();                  // also publishes idx_sh
  if (t == 0) atomicAdd(accum, (double)((wred[0] + wred[1]) + (wred[2] + wred[3])));

  // ---- write z_q_st = x + (c - x) with explicit fp32 roundings ----
#pragma unroll
  for (int i = 0; i < 16; ++i) {
    int fi  = t + i * NTHREADS;
    int row = fi >> 6, dc = fi & 63;
    int code = idx_sh[row];
    float4 c4 = *reinterpret_cast<const float4*>(cb + (size_t)code * DDIM + dc * 4);
    float4 x4 = *reinterpret_cast<float4*>(&xs[row][dc * 4]);
    float4 o;
    o.x = __fadd_rn(x4.x, __fsub_rn(c4.x, x4.x));
    o.y = __fadd_rn(x4.y, __fsub_rn(c4.y, x4.y));
    o.z = __fadd_rn(x4.z, __fsub_rn(c4.z, x4.z));
    o.w = __fadd_rn(x4.w, __fsub_rn(c4.w, x4.w));
    *reinterpret_cast<float4*>(out + (size_t)(m0 + row) * DDIM + dc * 4) = o;
  }
}

// ---------------- final: loss scalar ----------------
__global__ void vq_final(const double* __restrict__ accum, float* __restrict__ out) {
  out[ZELEMS] = (float)(1.25 * accum[0] / (double)ZELEMS);
}

extern "C" void kernel_launch(void* const* d_in, const int* in_sizes, int n_in,
                              void* d_out, int out_size, void* d_ws, size_t ws_size,
                              hipStream_t stream) {
  const float* x  = (const float*)d_in[0];
  const float* cb = (const float*)d_in[1];
  float* out = (float*)d_out;
  float*  cnorm = (float*)d_ws;                          // 4096 floats
  double* accum = (double*)((char*)d_ws + 16384);        // 1 double

  vq_prep<<<KC / NTHREADS, NTHREADS, 0, stream>>>(cb, cnorm, accum);
  vq_main<<<MTOT / TM, NTHREADS, 0, stream>>>(x, cb, cnorm, out, accum);
  vq_final<<<1, 1, 0, stream>>>(accum, out);
}

// Round 3
// 441.257 us; speedup vs baseline: 3.5016x; 3.5016x over previous
//
#include <hip/hip_runtime.h>

#define MTOT 32768
#define KC   4096
#define DDIM 256
#define BM   128          // rows per block, phase 1
#define TKC  64           // codes per LDS tile
#define NT1  512
#define ZELEMS (MTOT * DDIM)
#define THRESH 6.0e-4f
#define WLCAP 32768

typedef _Float16 half8 __attribute__((ext_vector_type(8)));
typedef _Float16 half4 __attribute__((ext_vector_type(4)));
typedef float f32x4 __attribute__((ext_vector_type(4)));

// ---------- np-bit-exact helpers (verified round 2: absmax 0) ----------
__device__ __forceinline__ float sqr_rn(float v) { return __fmul_rn(v, v); }

__device__ __forceinline__ float np_sumsq_256(const float* p) {
  float half_[2];
#pragma unroll
  for (int h = 0; h < 2; ++h) {
    const float* q = p + h * 128;
    float r[8];
#pragma unroll
    for (int j = 0; j < 8; ++j) r[j] = sqr_rn(q[j]);
#pragma unroll
    for (int i = 8; i < 128; i += 8)
#pragma unroll
      for (int j = 0; j < 8; ++j) r[j] = __fadd_rn(r[j], sqr_rn(q[i + j]));
    half_[h] = __fadd_rn(__fadd_rn(__fadd_rn(r[0], r[1]), __fadd_rn(r[2], r[3])),
                         __fadd_rn(__fadd_rn(r[4], r[5]), __fadd_rn(r[6], r[7])));
  }
  return __fadd_rn(half_[0], half_[1]);
}

// ---------------- prep: S (np-exact), cnorm (np-exact), zero scalars ----------------
__global__ __launch_bounds__(256) void vq_prep(const float* __restrict__ x,
                                               const float* __restrict__ cb,
                                               float* __restrict__ S,
                                               float* __restrict__ cnorm,
                                               int* __restrict__ wl_count,
                                               double* __restrict__ accum) {
  int n = blockIdx.x * 256 + threadIdx.x;
  if (n == 0) { *accum = 0.0; *wl_count = 0; }
  if (n < MTOT) {
    S[n] = np_sumsq_256(x + (size_t)n * DDIM);
  } else {
    int k = n - MTOT;
    if (k < KC) cnorm[k] = np_sumsq_256(cb + (size_t)k * DDIM);
  }
}

// ---------------- phase 1: fp16 MFMA surrogate scoring + min1/min2/argmin ----------------
__global__ __launch_bounds__(NT1) void vq_score(const float* __restrict__ x,
                                                const float* __restrict__ cb,
                                                const float* __restrict__ Sarr,
                                                const float* __restrict__ cnorm,
                                                int* __restrict__ bestidx,
                                                int* __restrict__ wl,
                                                int* __restrict__ wl_count,
                                                double* __restrict__ accum) {
  __shared__ _Float16 xf[BM * DDIM];        // 64 KB  rows f16
  __shared__ _Float16 cbt[2][TKC * DDIM];   // 64 KB  codes f16 (scaled x256), XOR-swizzled
  __shared__ float cn[KC];                  // 16 KB
  __shared__ float wred[8];

  const int t = threadIdx.x;
  const int m0 = blockIdx.x * BM;
  const int lane = t & 63, w = t >> 6;
  const int lo = lane & 15, hi = lane >> 4;

  // ---- stage x tile as f16 (coalesced) ----
#pragma unroll
  for (int i = 0; i < 16; ++i) {
    int fi = t + i * NT1;
    int row = fi >> 6, dq = fi & 63;
    float4 v = *reinterpret_cast<const float4*>(x + (size_t)(m0 + row) * DDIM + dq * 4);
    half4 hv = { (_Float16)v.x, (_Float16)v.y, (_Float16)v.z, (_Float16)v.w };
    *reinterpret_cast<half4*>(&xf[row * DDIM + dq * 4]) = hv;
  }
  // ---- stage cnorm ----
#pragma unroll
  for (int i = 0; i < 2; ++i) {
    int fi = t + i * NT1;
    *reinterpret_cast<float4*>(&cn[fi * 4]) = *reinterpret_cast<const float4*>(cnorm + fi * 4);
  }
  // ---- stage code tile 0 (f16, scaled x256, swizzled) ----
  const int cl = t >> 3, ds8 = t & 7;   // code 0..63, d-segment 0..7 (32 d each)
  {
    const float* src = cb + (size_t)cl * DDIM + ds8 * 32;
#pragma unroll
    for (int j = 0; j < 4; ++j) {
      float4 A4 = *reinterpret_cast<const float4*>(src + j * 8);
      float4 B4 = *reinterpret_cast<const float4*>(src + j * 8 + 4);
      union { half8 v; _Float16 h[8]; } u;
      u.h[0] = (_Float16)(A4.x * 256.0f); u.h[1] = (_Float16)(A4.y * 256.0f);
      u.h[2] = (_Float16)(A4.z * 256.0f); u.h[3] = (_Float16)(A4.w * 256.0f);
      u.h[4] = (_Float16)(B4.x * 256.0f); u.h[5] = (_Float16)(B4.y * 256.0f);
      u.h[6] = (_Float16)(B4.z * 256.0f); u.h[7] = (_Float16)(B4.w * 256.0f);
      int fi = (cl * DDIM + ds8 * 32 + j * 8) ^ ((cl & 7) << 3);
      *reinterpret_cast<half8*>(&cbt[0][fi]) = u.v;
    }
  }
  __syncthreads();

  // ---- A fragments in registers: wave w owns rows w*16..+15 ----
  half8 a[8];
  const int arow = w * 16 + lo;
#pragma unroll
  for (int s = 0; s < 8; ++s)
    a[s] = *reinterpret_cast<half8*>(&xf[arow * DDIM + s * 32 + hi * 8]);

  float v1[4], v2[4]; int i1[4];
#pragma unroll
  for (int r = 0; r < 4; ++r) { v1[r] = 3.4e38f; v2[r] = 3.4e38f; i1[r] = 0; }

  for (int kt = 0; kt < KC / TKC; ++kt) {
    const int cur = kt & 1, nxt = cur ^ 1;
    float4 pf[8];
    if (kt < KC / TKC - 1) {
      const float* src = cb + (size_t)((kt + 1) * TKC + cl) * DDIM + ds8 * 32;
#pragma unroll
      for (int j = 0; j < 8; ++j) pf[j] = *reinterpret_cast<const float4*>(src + j * 4);
    }
    const int ktb = kt * TKC;
#pragma unroll
    for (int f = 0; f < 4; ++f) {
      const int code_l = f * 16 + lo;
      const int bswz = (code_l & 7) << 3;
      const int bbase = code_l * DDIM + hi * 8;
      f32x4 acc = {0.f, 0.f, 0.f, 0.f};
#pragma unroll
      for (int s = 0; s < 8; ++s) {
        half8 b = *reinterpret_cast<half8*>(&cbt[cur][(bbase + s * 32) ^ bswz]);
        acc = __builtin_amdgcn_mfma_f32_16x16x32_f16(a[s], b, acc, 0, 0, 0);
      }
      const float C = cn[ktb + code_l];
      const int code = ktb + code_l;
#pragma unroll
      for (int r = 0; r < 4; ++r) {
        // s = C - 2E ; acc = 256*E  ->  s = fma(acc, -1/128, C)
        float sv = fmaf(acc[r], -0.0078125f, C);
        bool lt = sv < v1[r];
        v2[r] = fminf(v2[r], lt ? v1[r] : sv);
        if (lt) { v1[r] = sv; i1[r] = code; }
      }
    }
    if (kt < KC / TKC - 1) {
#pragma unroll
      for (int j = 0; j < 4; ++j) {
        float4 A4 = pf[2 * j], B4 = pf[2 * j + 1];
        union { half8 v; _Float16 h[8]; } u;
        u.h[0] = (_Float16)(A4.x * 256.0f); u.h[1] = (_Float16)(A4.y * 256.0f);
        u.h[2] = (_Float16)(A4.z * 256.0f); u.h[3] = (_Float16)(A4.w * 256.0f);
        u.h[4] = (_Float16)(B4.x * 256.0f); u.h[5] = (_Float16)(B4.y * 256.0f);
        u.h[6] = (_Float16)(B4.z * 256.0f); u.h[7] = (_Float16)(B4.w * 256.0f);
        int fi = (cl * DDIM + ds8 * 32 + j * 8) ^ ((cl & 7) << 3);
        *reinterpret_cast<half8*>(&cbt[nxt][fi]) = u.v;
      }
    }
    __syncthreads();
  }

  // ---- argmin (+min2) reduce across the 16 lanes sharing each row ----
  float part = 0.f;
#pragma unroll
  for (int r = 0; r < 4; ++r) {
#pragma unroll
    for (int m = 1; m <= 8; m <<= 1) {
      float ov1 = __shfl_xor(v1[r], m, 64);
      int   oi  = __shfl_xor(i1[r], m, 64);
      float ov2 = __shfl_xor(v2[r], m, 64);
      float mx = fmaxf(v1[r], ov1);
      v2[r] = fminf(fminf(v2[r], ov2), mx);
      bool take = (ov1 < v1[r]) || (ov1 == v1[r] && oi < i1[r]);
      if (take) { v1[r] = ov1; i1[r] = oi; }
    }
    if (lo == 0) {
      int row = m0 + w * 16 + hi * 4 + r;
      bestidx[row] = i1[r];
      float Dmin = __fadd_rn(Sarr[row], v1[r]);
      float gap = v2[r] - v1[r];
      if (gap <= THRESH) {
        int pos = atomicAdd(wl_count, 1);
        if (pos < WLCAP) wl[pos] = row;
        else part += Dmin;          // overflow fallback (never expected)
      } else {
        part += Dmin;               // safe rows contribute approx D_min to loss
      }
    }
  }
#pragma unroll
  for (int off = 32; off >= 1; off >>= 1) part += __shfl_down(part, off, 64);
  if (lane == 0) wred[w] = part;
  __syncthreads();
  if (t == 0) {
    double s = 0.0;
#pragma unroll
    for (int i = 0; i < 8; ++i) s += (double)wred[i];
    atomicAdd(accum, s);
  }
}

// ---------------- phase 2: np-bit-exact rescore of ambiguous rows ----------------
__global__ __launch_bounds__(256) void vq_rescore(const float* __restrict__ x,
                                                  const float* __restrict__ cb,
                                                  const float* __restrict__ Sarr,
                                                  const float* __restrict__ cnorm,
                                                  int* __restrict__ bestidx,
                                                  const int* __restrict__ wl,
                                                  const int* __restrict__ wl_count,
                                                  double* __restrict__ accum) {
  const int cnt = *wl_count;
  const int e0 = blockIdx.x * 4;
  if (e0 >= cnt) return;

  __shared__ float xs[4][260];
  __shared__ float cst[TKC * DDIM];     // 64 KB fp32, XOR-swizzled
  __shared__ int rsh[4];
  __shared__ float redv[256];
  __shared__ int redi[256];

  const int t = threadIdx.x;
  if (t < 4) {
    int e = e0 + t;
    rsh[t] = wl[(e < cnt) ? e : e0];
  }
  __syncthreads();
  {
    int j = t >> 6, dq = t & 63;
    *reinterpret_cast<float4*>(&xs[j][dq * 4]) =
        *reinterpret_cast<const float4*>(x + (size_t)rsh[j] * DDIM + dq * 4);
  }
  const int row_l = t & 3, code_l = t >> 2;
  const float Sv = Sarr[rsh[row_l]];
  const int swz = (code_l & 7) << 2;

  float bestD = 3.4e38f; int bestI = 0x7fffffff;
  for (int tile = 0; tile < KC / TKC; ++tile) {
    __syncthreads();
    {
      int cs = t >> 2, dl = t & 3;
#pragma unroll
      for (int i = 0; i < 16; ++i) {
        int d = dl * 4 + i * 16;
        float4 v = *reinterpret_cast<const float4*>(cb + (size_t)(tile * TKC + cs) * DDIM + d);
        *reinterpret_cast<float4*>(&cst[(cs * DDIM + d) ^ ((cs & 7) << 2)]) = v;
      }
    }
    __syncthreads();
    // np einsum order: 4 lane accumulators, ascending d, mul-then-add
    float r0 = 0.f, r1 = 0.f, r2 = 0.f, r3 = 0.f;
    const int cb0 = code_l * DDIM;
#pragma unroll 4
    for (int dq = 0; dq < 64; ++dq) {
      float4 cv = *reinterpret_cast<float4*>(&cst[(cb0 + dq * 4) ^ swz]);
      float4 xv = *reinterpret_cast<float4*>(&xs[row_l][dq * 4]);
      r0 = __fadd_rn(r0, __fmul_rn(xv.x, cv.x));
      r1 = __fadd_rn(r1, __fmul_rn(xv.y, cv.y));
      r2 = __fadd_rn(r2, __fmul_rn(xv.z, cv.z));
      r3 = __fadd_rn(r3, __fmul_rn(xv.w, cv.w));
    }
    float e = __fadd_rn(__fadd_rn(r0, r1), __fadd_rn(r2, r3));
    int code = tile * TKC + code_l;
    float D = __fadd_rn(__fsub_rn(Sv, __fmul_rn(2.0f, e)), cnorm[code]);
    if (D < bestD || (D == bestD && code < bestI)) { bestD = D; bestI = code; }
  }
  redv[t] = bestD; redi[t] = bestI;
  __syncthreads();
  if (t < 4) {
    float bv = 3.4e38f; int bi = 0x7fffffff;
    for (int q = 0; q < 64; ++q) {
      float v = redv[t + q * 4]; int ii = redi[t + q * 4];
      if (v < bv || (v == bv && ii < bi)) { bv = v; bi = ii; }
    }
    if (e0 + t < cnt) {
      bestidx[rsh[t]] = bi;
      atomicAdd(accum, (double)bv);   // exact D_min for rescored rows
    }
  }
}

// ---------------- phase 3: emit z_q_st, indices ----------------
__global__ __launch_bounds__(256) void vq_emit(const float* __restrict__ x,
                                               const float* __restrict__ cb,
                                               const int* __restrict__ bestidx,
                                               float* __restrict__ out) {
  __shared__ int ish[64];
  const int t = threadIdx.x;
  const int m0 = blockIdx.x * 64;
  if (t < 64) {
    int ii = bestidx[m0 + t];
    ish[t] = ii;
    out[(size_t)ZELEMS + 1 + m0 + t] = (float)ii;
  }
  __syncthreads();
#pragma unroll
  for (int i = 0; i < 16; ++i) {
    int fi = t + i * 256;
    int row = fi >> 6, dc = fi & 63;
    int code = ish[row];
    float4 c4 = *reinterpret_cast<const float4*>(cb + (size_t)code * DDIM + dc * 4);
    float4 x4 = *reinterpret_cast<const float4*>(x + (size_t)(m0 + row) * DDIM + dc * 4);
    float4 o;
    o.x = __fadd_rn(x4.x, __fsub_rn(c4.x, x4.x));
    o.y = __fadd_rn(x4.y, __fsub_rn(c4.y, x4.y));
    o.z = __fadd_rn(x4.z, __fsub_rn(c4.z, x4.z));
    o.w = __fadd_rn(x4.w, __fsub_rn(c4.w, x4.w));
    *reinterpret_cast<float4*>(out + (size_t)(m0 + row) * DDIM + dc * 4) = o;
  }
}

// ---------------- final: loss scalar ----------------
__global__ void vq_final(const double* __restrict__ accum, float* __restrict__ out) {
  out[ZELEMS] = (float)(1.25 * accum[0] / (double)ZELEMS);
}

extern "C" void kernel_launch(void* const* d_in, const int* in_sizes, int n_in,
                              void* d_out, int out_size, void* d_ws, size_t ws_size,
                              hipStream_t stream) {
  const float* x  = (const float*)d_in[0];
  const float* cb = (const float*)d_in[1];
  float* out = (float*)d_out;

  char* ws = (char*)d_ws;
  float*  S        = (float*)(ws + 0);        // 128 KB
  float*  cnorm    = (float*)(ws + 131072);   // 16 KB
  int*    bestidx  = (int*)  (ws + 147456);   // 128 KB
  int*    wl       = (int*)  (ws + 278528);   // 128 KB
  int*    wl_count = (int*)  (ws + 409600);
  double* accum    = (double*)(ws + 409608);

  vq_prep<<<(MTOT + KC) / 256, 256, 0, stream>>>(x, cb, S, cnorm, wl_count, accum);
  vq_score<<<MTOT / BM, NT1, 0, stream>>>(x, cb, S, cnorm, bestidx, wl, wl_count, accum);
  vq_rescore<<<8192, 256, 0, stream>>>(x, cb, S, cnorm, bestidx, wl, wl_count, accum);
  vq_emit<<<MTOT / 64, 256, 0, stream>>>(x, cb, bestidx, out);
  vq_final<<<1, 1, 0, stream>>>(accum, out);
}

// Round 4
// 238.725 us; speedup vs baseline: 6.4724x; 1.8484x over previous
//
#include <hip/hip_runtime.h>

#define MTOT 32768
#define KC   4096
#define DDIM 256
#define BM   128          // rows per block, phase 1 (32 per wave)
#define TKC  64           // codes per LDS tile
#define ZELEMS (MTOT * DDIM)
#define THRESH 2.0e-4f
#define WLCAP 8192

typedef _Float16 half8 __attribute__((ext_vector_type(8)));
typedef _Float16 half4 __attribute__((ext_vector_type(4)));
typedef float f32x4 __attribute__((ext_vector_type(4)));

__device__ __forceinline__ void gload_lds16(const void* g, void* l) {
  __builtin_amdgcn_global_load_lds(
      (const __attribute__((address_space(1))) void*)g,
      (__attribute__((address_space(3))) void*)l, 16, 0, 0);
}

// ---------- np-bit-exact helpers (verified rounds 2-3: absmax 0) ----------
__device__ __forceinline__ float sqr_rn(float v) { return __fmul_rn(v, v); }

__device__ __forceinline__ float np_sumsq_256(const float* p) {
  float half_[2];
#pragma unroll
  for (int h = 0; h < 2; ++h) {
    const float* q = p + h * 128;
    float r[8];
#pragma unroll
    for (int j = 0; j < 8; ++j) r[j] = sqr_rn(q[j]);
#pragma unroll
    for (int i = 8; i < 128; i += 8)
#pragma unroll
      for (int j = 0; j < 8; ++j) r[j] = __fadd_rn(r[j], sqr_rn(q[i + j]));
    half_[h] = __fadd_rn(__fadd_rn(__fadd_rn(r[0], r[1]), __fadd_rn(r[2], r[3])),
                         __fadd_rn(__fadd_rn(r[4], r[5]), __fadd_rn(r[6], r[7])));
  }
  return __fadd_rn(half_[0], half_[1]);
}

// ---------------- prep: S (np-exact), cnorm (np-exact), zero scalars ----------------
__global__ __launch_bounds__(256) void vq_prep(const float* __restrict__ x,
                                               const float* __restrict__ cb,
                                               float* __restrict__ S,
                                               float* __restrict__ cnorm,
                                               int* __restrict__ wl_count,
                                               double* __restrict__ accum) {
  int n = blockIdx.x * 256 + threadIdx.x;
  if (n == 0) { *accum = 0.0; *wl_count = 0; }
  if (n < MTOT) {
    S[n] = np_sumsq_256(x + (size_t)n * DDIM);
  } else {
    int k = n - MTOT;
    if (k < KC) cnorm[k] = np_sumsq_256(cb + (size_t)k * DDIM);
  }
}

// ---------------- cvt: codebook -> f16 x256, pre-swizzled for linear LDS load ----
// LDS image wanted: cbt[(code*256 + d) ^ ((code&7)<<3)] = f16(cb[code][d]*256).
// XOR touches f16-index bits 3..5 only -> permutes 8-f16 chunks within a code row.
__global__ __launch_bounds__(256) void vq_cvt(const float* __restrict__ cb,
                                              _Float16* __restrict__ cbsw) {
  int k = blockIdx.x * 256 + threadIdx.x;    // code id 0..4095
  const float* src = cb + (size_t)k * DDIM;
  _Float16* dst = cbsw + (size_t)k * DDIM;   // k*256 == tile*16384 + code_l*256
  int sw = k & 7;
#pragma unroll 4
  for (int j = 0; j < 32; ++j) {
    float4 a4 = *reinterpret_cast<const float4*>(src + j * 8);
    float4 b4 = *reinterpret_cast<const float4*>(src + j * 8 + 4);
    union { half8 v; _Float16 h[8]; } u;
    u.h[0] = (_Float16)(a4.x * 256.0f); u.h[1] = (_Float16)(a4.y * 256.0f);
    u.h[2] = (_Float16)(a4.z * 256.0f); u.h[3] = (_Float16)(a4.w * 256.0f);
    u.h[4] = (_Float16)(b4.x * 256.0f); u.h[5] = (_Float16)(b4.y * 256.0f);
    u.h[6] = (_Float16)(b4.z * 256.0f); u.h[7] = (_Float16)(b4.w * 256.0f);
    *reinterpret_cast<half8*>(dst + ((j ^ sw) * 8)) = u.v;
  }
}

// ---------------- phase 1: f16 MFMA surrogate + min1/min2/argmin ----------------
// 4 waves x 32 rows each (2 A-frag sets) -> each B ds_read_b128 feeds 2 MFMAs.
__global__ __launch_bounds__(256) void vq_score(const float* __restrict__ x,
                                                const _Float16* __restrict__ cbsw,
                                                const float* __restrict__ Sarr,
                                                const float* __restrict__ cnorm,
                                                int* __restrict__ bestidx,
                                                int* __restrict__ wl,
                                                int* __restrict__ wl_count,
                                                double* __restrict__ accum) {
  __shared__ _Float16 xf[BM * DDIM];        // 64 KB
  __shared__ _Float16 cbt[2][TKC * DDIM];   // 2 x 32 KB, swizzled f16 code tiles
  __shared__ float cn[KC];                  // 16 KB
  __shared__ float wred[4];

  const int t = threadIdx.x;
  const int m0 = blockIdx.x * BM;
  const int lane = t & 63, w = t >> 6;
  const int lo = lane & 15, hi = lane >> 4;

  // ---- stage cn ----
#pragma unroll
  for (int i = 0; i < 4; ++i) {
    int fi = t + i * 256;
    *reinterpret_cast<float4*>(&cn[fi * 4]) = *reinterpret_cast<const float4*>(cnorm + fi * 4);
  }
  // ---- stage x tile as f16 (coalesced) ----
#pragma unroll
  for (int i = 0; i < 32; ++i) {
    int fi = t + i * 256;
    int row = fi >> 6, dq = fi & 63;
    float4 v = *reinterpret_cast<const float4*>(x + (size_t)(m0 + row) * DDIM + dq * 4);
    half4 hv = { (_Float16)v.x, (_Float16)v.y, (_Float16)v.z, (_Float16)v.w };
    *reinterpret_cast<half4*>(&xf[row * DDIM + dq * 4]) = hv;
  }
  // ---- issue async load of code tile 0 (pre-swizzled source, linear LDS dest) ----
#pragma unroll
  for (int j = 0; j < 8; ++j)
    gload_lds16(cbsw + 0 * 16384 + w * 4096 + j * 512 + lane * 8,
                &cbt[0][w * 4096 + j * 512]);
  __syncthreads();

  // ---- A fragments: wave w owns rows w*32 + s2*16 + lo ----
  half8 a[2][8];
#pragma unroll
  for (int s2 = 0; s2 < 2; ++s2) {
    int arow = w * 32 + s2 * 16 + lo;
#pragma unroll
    for (int s = 0; s < 8; ++s)
      a[s2][s] = *reinterpret_cast<half8*>(&xf[arow * DDIM + s * 32 + hi * 8]);
  }

  float v1[2][4], v2[2][4]; int i1[2][4];
#pragma unroll
  for (int s2 = 0; s2 < 2; ++s2)
#pragma unroll
    for (int r = 0; r < 4; ++r) { v1[s2][r] = 3.4e38f; v2[s2][r] = 3.4e38f; i1[s2][r] = 0; }

  for (int kt = 0; kt < KC / TKC; ++kt) {
    const int cur = kt & 1;
    if (kt < KC / TKC - 1) {
#pragma unroll
      for (int j = 0; j < 8; ++j)
        gload_lds16(cbsw + (size_t)(kt + 1) * 16384 + w * 4096 + j * 512 + lane * 8,
                    &cbt[cur ^ 1][w * 4096 + j * 512]);
    }
    const int ktb = kt * TKC;
#pragma unroll
    for (int cf = 0; cf < 4; ++cf) {
      const int code_l = cf * 16 + lo;
      const int bswz = (code_l & 7) << 3;
      const int bbase = code_l * DDIM + hi * 8;
      f32x4 acc0 = {0.f, 0.f, 0.f, 0.f}, acc1 = {0.f, 0.f, 0.f, 0.f};
#pragma unroll
      for (int s = 0; s < 8; ++s) {
        half8 b = *reinterpret_cast<half8*>(&cbt[cur][(bbase + s * 32) ^ bswz]);
        acc0 = __builtin_amdgcn_mfma_f32_16x16x32_f16(a[0][s], b, acc0, 0, 0, 0);
        acc1 = __builtin_amdgcn_mfma_f32_16x16x32_f16(a[1][s], b, acc1, 0, 0, 0);
      }
      const float C = cn[ktb + code_l];
      const int code = ktb + code_l;
#pragma unroll
      for (int r = 0; r < 4; ++r) {
        // s = C - 2E ; acc = 256*E  ->  s = fma(acc, -1/128, C)
        float s0 = fmaf(acc0[r], -0.0078125f, C);
        bool lt0 = s0 < v1[0][r];
        v2[0][r] = fminf(v2[0][r], lt0 ? v1[0][r] : s0);
        if (lt0) { v1[0][r] = s0; i1[0][r] = code; }
        float s1 = fmaf(acc1[r], -0.0078125f, C);
        bool lt1 = s1 < v1[1][r];
        v2[1][r] = fminf(v2[1][r], lt1 ? v1[1][r] : s1);
        if (lt1) { v1[1][r] = s1; i1[1][r] = code; }
      }
    }
    __syncthreads();   // drains global_load_lds (vmcnt) + protects cbt[cur^1]
  }

  // ---- argmin (+min2) reduce across the 16 lanes (lo) sharing each row ----
  float part = 0.f;
#pragma unroll
  for (int s2 = 0; s2 < 2; ++s2) {
#pragma unroll
    for (int r = 0; r < 4; ++r) {
      float v = v1[s2][r], u = v2[s2][r]; int ii = i1[s2][r];
#pragma unroll
      for (int m = 1; m <= 8; m <<= 1) {
        float ov = __shfl_xor(v, m, 64);
        int   oi = __shfl_xor(ii, m, 64);
        float ou = __shfl_xor(u, m, 64);
        float mx = fmaxf(v, ov);
        u = fminf(fminf(u, ou), mx);
        bool take = (ov < v) || (ov == v && oi < ii);
        if (take) { v = ov; ii = oi; }
      }
      if (lo == 0) {
        int row = m0 + w * 32 + s2 * 16 + hi * 4 + r;
        bestidx[row] = ii;
        float gap = u - v;
        if (gap <= THRESH) {
          int pos = atomicAdd(wl_count, 1);
          if (pos >= WLCAP) part += __fadd_rn(Sarr[row], v);  // overflow fallback
          else wl[pos] = row;
        } else {
          part += __fadd_rn(Sarr[row], v);   // safe rows: approx D_min to loss
        }
      }
    }
  }
#pragma unroll
  for (int off = 32; off >= 1; off >>= 1) part += __shfl_down(part, off, 64);
  if (lane == 0) wred[w] = part;
  __syncthreads();
  if (t == 0)
    atomicAdd(accum, (double)((wred[0] + wred[1]) + (wred[2] + wred[3])));
}

// ---------------- phase 2: np-bit-exact rescore, code axis split 8x ----------------
__global__ __launch_bounds__(256) void vq_rescore(const float* __restrict__ x,
                                                  const float* __restrict__ cb,
                                                  const float* __restrict__ Sarr,
                                                  const float* __restrict__ cnorm,
                                                  const int* __restrict__ wl,
                                                  const int* __restrict__ wl_count,
                                                  float* __restrict__ pD,
                                                  int* __restrict__ pI) {
  const int cnt = min(*wl_count, WLCAP);
  if (cnt == 0) return;
  const int chunk = blockIdx.x & 7;       // 512-code chunk
  const int g0 = blockIdx.x >> 3;         // row group (4 rows)
  const int ngroups = (cnt + 3) >> 2;

  __shared__ float xs[4][260];
  __shared__ float cst[TKC * DDIM];       // 64 KB fp32, XOR-swizzled
  __shared__ int rsh[4];
  __shared__ float redv[256];
  __shared__ int redi[256];

  const int t = threadIdx.x;
  const int row_l = t & 3, code_l = t >> 2;
  const int swz = (code_l & 7) << 2;

  for (int g = g0; g < ngroups; g += 256) {
    if (t < 4) { int e = g * 4 + t; rsh[t] = wl[(e < cnt) ? e : g * 4]; }
    __syncthreads();
    { int j = t >> 6, dq = t & 63;
      *reinterpret_cast<float4*>(&xs[j][dq * 4]) =
          *reinterpret_cast<const float4*>(x + (size_t)rsh[j] * DDIM + dq * 4); }
    const float Sv = Sarr[rsh[row_l]];

    float bestD = 3.4e38f; int bestI = 0x7fffffff;
    for (int tile = 0; tile < 8; ++tile) {
      __syncthreads();
      { int cs = t >> 2, dl = t & 3;
        const float* src = cb + (size_t)(chunk * 512 + tile * TKC + cs) * DDIM;
#pragma unroll
        for (int i = 0; i < 16; ++i) {
          int d = dl * 4 + i * 16;
          *reinterpret_cast<float4*>(&cst[(cs * DDIM + d) ^ ((cs & 7) << 2)]) =
              *reinterpret_cast<const float4*>(src + d);
        } }
      __syncthreads();
      // np einsum order: 4 lane accumulators, ascending d, mul-then-add
      float r0 = 0.f, r1 = 0.f, r2 = 0.f, r3 = 0.f;
      const int cb0 = code_l * DDIM;
#pragma unroll 4
      for (int dq = 0; dq < 64; ++dq) {
        float4 cv = *reinterpret_cast<float4*>(&cst[(cb0 + dq * 4) ^ swz]);
        float4 xv = *reinterpret_cast<float4*>(&xs[row_l][dq * 4]);
        r0 = __fadd_rn(r0, __fmul_rn(xv.x, cv.x));
        r1 = __fadd_rn(r1, __fmul_rn(xv.y, cv.y));
        r2 = __fadd_rn(r2, __fmul_rn(xv.z, cv.z));
        r3 = __fadd_rn(r3, __fmul_rn(xv.w, cv.w));
      }
      float e = __fadd_rn(__fadd_rn(r0, r1), __fadd_rn(r2, r3));
      int code = chunk * 512 + tile * TKC + code_l;
      float D = __fadd_rn(__fsub_rn(Sv, __fmul_rn(2.0f, e)), cnorm[code]);
      if (D < bestD || (D == bestD && code < bestI)) { bestD = D; bestI = code; }
    }
    redv[t] = bestD; redi[t] = bestI;
    __syncthreads();
    if (t < 4) {
      float bv = 3.4e38f; int bi = 0x7fffffff;
      for (int q = 0; q < 64; ++q) {
        float v = redv[t + q * 4]; int ii = redi[t + q * 4];
        if (v < bv || (v == bv && ii < bi)) { bv = v; bi = ii; }
      }
      int rpos = g * 4 + t;
      if (rpos < cnt) { pD[rpos * 8 + chunk] = bv; pI[rpos * 8 + chunk] = bi; }
    }
    __syncthreads();
  }
}

// ---------------- combine chunk partials: lexicographic min over 8 ----------------
__global__ __launch_bounds__(256) void vq_combine(const int* __restrict__ wl,
                                                  const int* __restrict__ wl_count,
                                                  const float* __restrict__ pD,
                                                  const int* __restrict__ pI,
                                                  int* __restrict__ bestidx,
                                                  double* __restrict__ accum) {
  const int cnt = min(*wl_count, WLCAP);
  for (int r = blockIdx.x * 256 + threadIdx.x; r < cnt; r += gridDim.x * 256) {
    float bv = 3.4e38f; int bi = 0x7fffffff;
#pragma unroll
    for (int c = 0; c < 8; ++c) {
      float v = pD[r * 8 + c]; int ii = pI[r * 8 + c];
      if (v < bv || (v == bv && ii < bi)) { bv = v; bi = ii; }
    }
    bestidx[wl[r]] = bi;
    atomicAdd(accum, (double)bv);    // exact D_min for rescored rows
  }
}

// ---------------- phase 3: emit z_q_st, indices ----------------
__global__ __launch_bounds__(256) void vq_emit(const float* __restrict__ x,
                                               const float* __restrict__ cb,
                                               const int* __restrict__ bestidx,
                                               float* __restrict__ out) {
  __shared__ int ish[64];
  const int t = threadIdx.x;
  const int m0 = blockIdx.x * 64;
  if (t < 64) {
    int ii = bestidx[m0 + t];
    ish[t] = ii;
    out[(size_t)ZELEMS + 1 + m0 + t] = (float)ii;
  }
  __syncthreads();
#pragma unroll
  for (int i = 0; i < 16; ++i) {
    int fi = t + i * 256;
    int row = fi >> 6, dc = fi & 63;
    int code = ish[row];
    float4 c4 = *reinterpret_cast<const float4*>(cb + (size_t)code * DDIM + dc * 4);
    float4 x4 = *reinterpret_cast<const float4*>(x + (size_t)(m0 + row) * DDIM + dc * 4);
    float4 o;
    o.x = __fadd_rn(x4.x, __fsub_rn(c4.x, x4.x));
    o.y = __fadd_rn(x4.y, __fsub_rn(c4.y, x4.y));
    o.z = __fadd_rn(x4.z, __fsub_rn(c4.z, x4.z));
    o.w = __fadd_rn(x4.w, __fsub_rn(c4.w, x4.w));
    *reinterpret_cast<float4*>(out + (size_t)(m0 + row) * DDIM + dc * 4) = o;
  }
}

// ---------------- final: loss scalar ----------------
__global__ void vq_final(const double* __restrict__ accum, float* __restrict__ out) {
  out[ZELEMS] = (float)(1.25 * accum[0] / (double)ZELEMS);
}

extern "C" void kernel_launch(void* const* d_in, const int* in_sizes, int n_in,
                              void* d_out, int out_size, void* d_ws, size_t ws_size,
                              hipStream_t stream) {
  const float* x  = (const float*)d_in[0];
  const float* cb = (const float*)d_in[1];
  float* out = (float*)d_out;

  char* ws = (char*)d_ws;
  float*     S        = (float*)(ws + 0);          // 128 KB
  float*     cnorm    = (float*)(ws + 131072);     // 16 KB
  int*       bestidx  = (int*)  (ws + 147456);     // 128 KB
  int*       wl       = (int*)  (ws + 278528);     // 32 KB
  int*       wl_count = (int*)  (ws + 311296);
  double*    accum    = (double*)(ws + 311312);
  float*     pD       = (float*)(ws + 315392);     // 256 KB
  int*       pI       = (int*)  (ws + 577536);     // 256 KB
  _Float16*  cbsw     = (_Float16*)(ws + 839680);  // 2 MB, swizzled f16 codebook

  vq_prep<<<(MTOT + KC) / 256, 256, 0, stream>>>(x, cb, S, cnorm, wl_count, accum);
  vq_cvt<<<KC / 256, 256, 0, stream>>>(cb, cbsw);
  vq_score<<<MTOT / BM, 256, 0, stream>>>(x, cbsw, S, cnorm, bestidx, wl, wl_count, accum);
  vq_rescore<<<2048, 256, 0, stream>>>(x, cb, S, cnorm, wl, wl_count, pD, pI);
  vq_combine<<<8, 256, 0, stream>>>(wl, wl_count, pD, pI, bestidx, accum);
  vq_emit<<<MTOT / 64, 256, 0, stream>>>(x, cb, bestidx, out);
  vq_final<<<1, 1, 0, stream>>>(accum, out);
}

// Round 5
// 222.002 us; speedup vs baseline: 6.9600x; 1.0753x over previous
//
#include <hip/hip_runtime.h>

#define MTOT 32768
#define KC   4096
#define DDIM 256
#define BM   128          // rows per block, phase 1
#define TKC  64           // codes per LDS tile
#define ZELEMS (MTOT * DDIM)
#define THRESH 2.0e-4f
#define WLCAP 8192

typedef _Float16 half8 __attribute__((ext_vector_type(8)));
typedef _Float16 half4 __attribute__((ext_vector_type(4)));
typedef float f32x4 __attribute__((ext_vector_type(4)));

__device__ __forceinline__ void gload_lds16(const void* g, void* l) {
  __builtin_amdgcn_global_load_lds(
      (const __attribute__((address_space(1))) void*)g,
      (__attribute__((address_space(3))) void*)l, 16, 0, 0);
}

// ---------- np-bit-exact helpers (verified rounds 2-4: absmax 0) ----------
__device__ __forceinline__ float sqr_rn(float v) { return __fmul_rn(v, v); }

__device__ __forceinline__ float np_sumsq_256(const float* p) {
  float half_[2];
#pragma unroll
  for (int h = 0; h < 2; ++h) {
    const float* q = p + h * 128;
    float r[8];
#pragma unroll
    for (int j = 0; j < 8; ++j) r[j] = sqr_rn(q[j]);
#pragma unroll
    for (int i = 8; i < 128; i += 8)
#pragma unroll
      for (int j = 0; j < 8; ++j) r[j] = __fadd_rn(r[j], sqr_rn(q[i + j]));
    half_[h] = __fadd_rn(__fadd_rn(__fadd_rn(r[0], r[1]), __fadd_rn(r[2], r[3])),
                         __fadd_rn(__fadd_rn(r[4], r[5]), __fadd_rn(r[6], r[7])));
  }
  return __fadd_rn(half_[0], half_[1]);
}

// ---------------- prep: S (np-exact), cnorm (np-exact), zero scalars ----------------
__global__ __launch_bounds__(256) void vq_prep(const float* __restrict__ x,
                                               const float* __restrict__ cb,
                                               float* __restrict__ S,
                                               float* __restrict__ cnorm,
                                               int* __restrict__ wl_count,
                                               double* __restrict__ accum) {
  int n = blockIdx.x * 256 + threadIdx.x;
  if (n == 0) { *accum = 0.0; *wl_count = 0; }
  if (n < MTOT) {
    S[n] = np_sumsq_256(x + (size_t)n * DDIM);
  } else {
    int k = n - MTOT;
    if (k < KC) cnorm[k] = np_sumsq_256(cb + (size_t)k * DDIM);
  }
}

// ---------------- cvt: codebook -> f16 x256, pre-swizzled for linear LDS load ----
__global__ __launch_bounds__(256) void vq_cvt(const float* __restrict__ cb,
                                              _Float16* __restrict__ cbsw) {
  int k = blockIdx.x * 256 + threadIdx.x;    // code id 0..4095
  const float* src = cb + (size_t)k * DDIM;
  _Float16* dst = cbsw + (size_t)k * DDIM;
  int sw = k & 7;
#pragma unroll 4
  for (int j = 0; j < 32; ++j) {
    float4 a4 = *reinterpret_cast<const float4*>(src + j * 8);
    float4 b4 = *reinterpret_cast<const float4*>(src + j * 8 + 4);
    union { half8 v; _Float16 h[8]; } u;
    u.h[0] = (_Float16)(a4.x * 256.0f); u.h[1] = (_Float16)(a4.y * 256.0f);
    u.h[2] = (_Float16)(a4.z * 256.0f); u.h[3] = (_Float16)(a4.w * 256.0f);
    u.h[4] = (_Float16)(b4.x * 256.0f); u.h[5] = (_Float16)(b4.y * 256.0f);
    u.h[6] = (_Float16)(b4.z * 256.0f); u.h[7] = (_Float16)(b4.w * 256.0f);
    *reinterpret_cast<half8*>(dst + ((j ^ sw) * 8)) = u.v;
  }
}

// ---------------- phase 1: f16 MFMA surrogate + min1/min2/argmin ----------------
// 512 thr = 8 waves: wave = (rg = w>>2) row-half x (cg = w&3) code-quarter.
// Each wave: 64 rows (4 A-sets) x 16 codes -> every B ds_read feeds 4 MFMAs.
__global__ __launch_bounds__(512, 2) void vq_score(const float* __restrict__ x,
                                                   const _Float16* __restrict__ cbsw,
                                                   const float* __restrict__ Sarr,
                                                   const float* __restrict__ cnorm,
                                                   int* __restrict__ bestidx,
                                                   int* __restrict__ wl,
                                                   int* __restrict__ wl_count,
                                                   double* __restrict__ accum) {
  __shared__ _Float16 xf[BM * DDIM];        // 64 KB, XOR-swizzled; reused as scratch later
  __shared__ _Float16 cbt[2][TKC * DDIM];   // 2 x 32 KB, swizzled f16 code tiles
  __shared__ float wred[8];

  const int t = threadIdx.x;
  const int m0 = blockIdx.x * BM;
  const int lane = t & 63, w = t >> 6;
  const int lo = lane & 15, hi = lane >> 4;
  const int rg = w >> 2, cg = w & 3;

  // ---- stage x tile as f16, swizzled: idx = (row*256+dq*4) ^ ((row&7)<<3) ----
#pragma unroll
  for (int i = 0; i < 16; ++i) {
    int fi = t + i * 512;
    int row = fi >> 6, dq = fi & 63;
    float4 v = *reinterpret_cast<const float4*>(x + (size_t)(m0 + row) * DDIM + dq * 4);
    half4 hv = { (_Float16)v.x, (_Float16)v.y, (_Float16)v.z, (_Float16)v.w };
    *reinterpret_cast<half4*>(&xf[(row * DDIM + dq * 4) ^ ((row & 7) << 3)]) = hv;
  }
  // ---- issue async load of code tile 0 (pre-swizzled source, linear LDS dest) ----
#pragma unroll
  for (int j = 0; j < 4; ++j)
    gload_lds16(cbsw + w * 2048 + j * 512 + lane * 8,
                &cbt[0][w * 2048 + j * 512]);
  __syncthreads();

  // ---- A fragments: set s2 covers rows rg*64 + s2*16 + lo ----
  half8 a[4][8];
#pragma unroll
  for (int s2 = 0; s2 < 4; ++s2) {
    int arow = rg * 64 + s2 * 16 + lo;
#pragma unroll
    for (int s = 0; s < 8; ++s)
      a[s2][s] = *reinterpret_cast<half8*>(
          &xf[(arow * DDIM + s * 32 + hi * 8) ^ ((arow & 7) << 3)]);
  }

  const int code_l = cg * 16 + lo;          // code within tile
  const int bswz = (lo & 7) << 3;

  float v1[4][4], v2[4][4]; int i1[4][4];
#pragma unroll
  for (int s2 = 0; s2 < 4; ++s2)
#pragma unroll
    for (int r = 0; r < 4; ++r) { v1[s2][r] = 3.4e38f; v2[s2][r] = 3.4e38f; i1[s2][r] = 0; }

  for (int kt = 0; kt < KC / TKC; ++kt) {
    const int cur = kt & 1;
    if (kt < KC / TKC - 1) {
#pragma unroll
      for (int j = 0; j < 4; ++j)
        gload_lds16(cbsw + (size_t)(kt + 1) * 16384 + w * 2048 + j * 512 + lane * 8,
                    &cbt[cur ^ 1][w * 2048 + j * 512]);
    }
    const int ktb = kt * TKC;
    const float C = cnorm[ktb + code_l];     // L1/L2-resident, 16 distinct per wave
    f32x4 acc[4];
#pragma unroll
    for (int s2 = 0; s2 < 4; ++s2) acc[s2] = (f32x4){0.f, 0.f, 0.f, 0.f};
#pragma unroll
    for (int s = 0; s < 8; ++s) {
      half8 b = *reinterpret_cast<half8*>(
          &cbt[cur][(code_l * DDIM + s * 32 + hi * 8) ^ bswz]);
      acc[0] = __builtin_amdgcn_mfma_f32_16x16x32_f16(a[0][s], b, acc[0], 0, 0, 0);
      acc[1] = __builtin_amdgcn_mfma_f32_16x16x32_f16(a[1][s], b, acc[1], 0, 0, 0);
      acc[2] = __builtin_amdgcn_mfma_f32_16x16x32_f16(a[2][s], b, acc[2], 0, 0, 0);
      acc[3] = __builtin_amdgcn_mfma_f32_16x16x32_f16(a[3][s], b, acc[3], 0, 0, 0);
    }
    const int code = ktb + code_l;
#pragma unroll
    for (int s2 = 0; s2 < 4; ++s2) {
#pragma unroll
      for (int r = 0; r < 4; ++r) {
        // s = C - 2E ; acc = 256*E  ->  s = fma(acc, -1/128, C)
        float sv = fmaf(acc[s2][r], -0.0078125f, C);
        bool lt = sv < v1[s2][r];
        v2[s2][r] = fminf(v2[s2][r], lt ? v1[s2][r] : sv);
        if (lt) { v1[s2][r] = sv; i1[s2][r] = code; }
      }
    }
    __syncthreads();   // drains global_load_lds + protects cbt[cur^1]
  }

  // ---- per-wave reduce across the 16 lo-lanes sharing each row ----
  float* scrV1 = reinterpret_cast<float*>(xf);        // [4][128] (xf is dead)
  float* scrV2 = scrV1 + 512;
  int*   scrI1 = reinterpret_cast<int*>(scrV2 + 512);
#pragma unroll
  for (int s2 = 0; s2 < 4; ++s2) {
#pragma unroll
    for (int r = 0; r < 4; ++r) {
      float v = v1[s2][r], u = v2[s2][r]; int ii = i1[s2][r];
#pragma unroll
      for (int m = 1; m <= 8; m <<= 1) {
        float ov = __shfl_xor(v, m, 64);
        int   oi = __shfl_xor(ii, m, 64);
        float ou = __shfl_xor(u, m, 64);
        float mx = fmaxf(v, ov);
        u = fminf(fminf(u, ou), mx);
        bool take = (ov < v) || (ov == v && oi < ii);
        if (take) { v = ov; ii = oi; }
      }
      if (lo == 0) {
        int rowl = rg * 64 + s2 * 16 + hi * 4 + r;
        scrV1[cg * 128 + rowl] = v;
        scrV2[cg * 128 + rowl] = u;
        scrI1[cg * 128 + rowl] = ii;
      }
    }
  }
  __syncthreads();

  // ---- combine the 4 code-quarter candidates per row ----
  float part = 0.f;
  if (t < BM) {
    float bv1 = 3.4e38f, bv2 = 3.4e38f; int bi1 = 0x7fffffff;
#pragma unroll
    for (int c = 0; c < 4; ++c) {
      float v = scrV1[c * 128 + t];
      float u = scrV2[c * 128 + t];
      int  ii = scrI1[c * 128 + t];
      float mx = fmaxf(bv1, v);
      bv2 = fminf(fminf(bv2, u), mx);
      if (v < bv1 || (v == bv1 && ii < bi1)) { bv1 = v; bi1 = ii; }
    }
    int row = m0 + t;
    bestidx[row] = bi1;
    float gap = bv2 - bv1;
    if (gap <= THRESH) {
      int pos = atomicAdd(wl_count, 1);
      if (pos >= WLCAP) part = __fadd_rn(Sarr[row], bv1);   // overflow fallback
      else wl[pos] = row;
    } else {
      part = __fadd_rn(Sarr[row], bv1);    // safe rows: approx D_min to loss
    }
  }
#pragma unroll
  for (int off = 32; off >= 1; off >>= 1) part += __shfl_down(part, off, 64);
  if (lane == 0) wred[w] = part;
  __syncthreads();
  if (t == 0) {
    double s = 0.0;
#pragma unroll
    for (int i = 0; i < 8; ++i) s += (double)wred[i];
    atomicAdd(accum, s);
  }
}

// ---------------- phase 2: np-bit-exact rescore, 8 rows x 512-code chunk ----------------
__global__ __launch_bounds__(512) void vq_rescore(const float* __restrict__ x,
                                                  const float* __restrict__ cb,
                                                  const float* __restrict__ Sarr,
                                                  const float* __restrict__ cnorm,
                                                  const int* __restrict__ wl,
                                                  const int* __restrict__ wl_count,
                                                  float* __restrict__ pD,
                                                  int* __restrict__ pI) {
  const int cnt = min(*wl_count, WLCAP);
  if (cnt == 0) return;
  const int chunk = blockIdx.x & 7;       // 512-code chunk
  const int g0 = blockIdx.x >> 3;         // row group (8 rows)
  const int ngroups = (cnt + 7) >> 3;

  __shared__ float xs[8][260];
  __shared__ float cst[TKC * DDIM];       // 64 KB fp32, XOR-swizzled
  __shared__ int rsh[8];
  __shared__ float redv[512];
  __shared__ int redi[512];

  const int t = threadIdx.x;
  const int row_l = t & 7, code_l = t >> 3;   // 8 rows x 64 codes
  const int swz = (code_l & 7) << 2;

  for (int g = g0; g < ngroups; g += 128) {
    if (t < 8) { int e = g * 8 + t; rsh[t] = wl[(e < cnt) ? e : g * 8]; }
    __syncthreads();
    { int j = t >> 6, dq = t & 63;
      *reinterpret_cast<float4*>(&xs[j][dq * 4]) =
          *reinterpret_cast<const float4*>(x + (size_t)rsh[j] * DDIM + dq * 4); }
    const float Sv = Sarr[rsh[row_l]];

    float bestD = 3.4e38f; int bestI = 0x7fffffff;
    for (int tile = 0; tile < 8; ++tile) {
      __syncthreads();
      { int cs = t >> 3, dl = t & 7;
        const float* src = cb + (size_t)(chunk * 512 + tile * TKC + cs) * DDIM;
#pragma unroll
        for (int i = 0; i < 8; ++i) {
          int d = dl * 4 + i * 32;
          *reinterpret_cast<float4*>(&cst[(cs * DDIM + d) ^ ((cs & 7) << 2)]) =
              *reinterpret_cast<const float4*>(src + d);
        } }
      __syncthreads();
      // np einsum order: 4 lane accumulators, ascending d, mul-then-add
      float r0 = 0.f, r1 = 0.f, r2 = 0.f, r3 = 0.f;
      const int cb0 = code_l * DDIM;
#pragma unroll 4
      for (int dq = 0; dq < 64; ++dq) {
        float4 cv = *reinterpret_cast<float4*>(&cst[(cb0 + dq * 4) ^ swz]);
        float4 xv = *reinterpret_cast<float4*>(&xs[row_l][dq * 4]);
        r0 = __fadd_rn(r0, __fmul_rn(xv.x, cv.x));
        r1 = __fadd_rn(r1, __fmul_rn(xv.y, cv.y));
        r2 = __fadd_rn(r2, __fmul_rn(xv.z, cv.z));
        r3 = __fadd_rn(r3, __fmul_rn(xv.w, cv.w));
      }
      float e = __fadd_rn(__fadd_rn(r0, r1), __fadd_rn(r2, r3));
      int code = chunk * 512 + tile * TKC + code_l;
      float D = __fadd_rn(__fsub_rn(Sv, __fmul_rn(2.0f, e)), cnorm[code]);
      if (D < bestD || (D == bestD && code < bestI)) { bestD = D; bestI = code; }
    }
    redv[t] = bestD; redi[t] = bestI;
    __syncthreads();
    if (t < 8) {
      float bv = 3.4e38f; int bi = 0x7fffffff;
      for (int q = 0; q < 64; ++q) {
        float v = redv[t + q * 8]; int ii = redi[t + q * 8];
        if (v < bv || (v == bv && ii < bi)) { bv = v; bi = ii; }
      }
      int rpos = g * 8 + t;
      if (rpos < cnt) { pD[rpos * 8 + chunk] = bv; pI[rpos * 8 + chunk] = bi; }
    }
    __syncthreads();
  }
}

// ---------------- combine chunk partials: lexicographic min over 8 ----------------
__global__ __launch_bounds__(256) void vq_combine(const int* __restrict__ wl,
                                                  const int* __restrict__ wl_count,
                                                  const float* __restrict__ pD,
                                                  const int* __restrict__ pI,
                                                  int* __restrict__ bestidx,
                                                  double* __restrict__ accum) {
  const int cnt = min(*wl_count, WLCAP);
  for (int r = blockIdx.x * 256 + threadIdx.x; r < cnt; r += gridDim.x * 256) {
    float bv = 3.4e38f; int bi = 0x7fffffff;
#pragma unroll
    for (int c = 0; c < 8; ++c) {
      float v = pD[r * 8 + c]; int ii = pI[r * 8 + c];
      if (v < bv || (v == bv && ii < bi)) { bv = v; bi = ii; }
    }
    bestidx[wl[r]] = bi;
    atomicAdd(accum, (double)bv);    // exact D_min for rescored rows
  }
}

// ---------------- phase 3: emit z_q_st, indices ----------------
__global__ __launch_bounds__(256) void vq_emit(const float* __restrict__ x,
                                               const float* __restrict__ cb,
                                               const int* __restrict__ bestidx,
                                               float* __restrict__ out) {
  __shared__ int ish[64];
  const int t = threadIdx.x;
  const int m0 = blockIdx.x * 64;
  if (t < 64) {
    int ii = bestidx[m0 + t];
    ish[t] = ii;
    out[(size_t)ZELEMS + 1 + m0 + t] = (float)ii;
  }
  __syncthreads();
#pragma unroll
  for (int i = 0; i < 16; ++i) {
    int fi = t + i * 256;
    int row = fi >> 6, dc = fi & 63;
    int code = ish[row];
    float4 c4 = *reinterpret_cast<const float4*>(cb + (size_t)code * DDIM + dc * 4);
    float4 x4 = *reinterpret_cast<const float4*>(x + (size_t)(m0 + row) * DDIM + dc * 4);
    float4 o;
    o.x = __fadd_rn(x4.x, __fsub_rn(c4.x, x4.x));
    o.y = __fadd_rn(x4.y, __fsub_rn(c4.y, x4.y));
    o.z = __fadd_rn(x4.z, __fsub_rn(c4.z, x4.z));
    o.w = __fadd_rn(x4.w, __fsub_rn(c4.w, x4.w));
    *reinterpret_cast<float4*>(out + (size_t)(m0 + row) * DDIM + dc * 4) = o;
  }
}

// ---------------- final: loss scalar ----------------
__global__ void vq_final(const double* __restrict__ accum, float* __restrict__ out) {
  out[ZELEMS] = (float)(1.25 * accum[0] / (double)ZELEMS);
}

extern "C" void kernel_launch(void* const* d_in, const int* in_sizes, int n_in,
                              void* d_out, int out_size, void* d_ws, size_t ws_size,
                              hipStream_t stream) {
  const float* x  = (const float*)d_in[0];
  const float* cb = (const float*)d_in[1];
  float* out = (float*)d_out;

  char* ws = (char*)d_ws;
  float*     S        = (float*)(ws + 0);          // 128 KB
  float*     cnorm    = (float*)(ws + 131072);     // 16 KB
  int*       bestidx  = (int*)  (ws + 147456);     // 128 KB
  int*       wl       = (int*)  (ws + 278528);     // 32 KB
  int*       wl_count = (int*)  (ws + 311296);
  double*    accum    = (double*)(ws + 311312);
  float*     pD       = (float*)(ws + 315392);     // 256 KB
  int*       pI       = (int*)  (ws + 577536);     // 256 KB
  _Float16*  cbsw     = (_Float16*)(ws + 839680);  // 2 MB, swizzled f16 codebook

  vq_prep<<<(MTOT + KC) / 256, 256, 0, stream>>>(x, cb, S, cnorm, wl_count, accum);
  vq_cvt<<<KC / 256, 256, 0, stream>>>(cb, cbsw);
  vq_score<<<MTOT / BM, 512, 0, stream>>>(x, cbsw, S, cnorm, bestidx, wl, wl_count, accum);
  vq_rescore<<<1024, 512, 0, stream>>>(x, cb, S, cnorm, wl, wl_count, pD, pI);
  vq_combine<<<8, 256, 0, stream>>>(wl, wl_count, pD, pI, bestidx, accum);
  vq_emit<<<MTOT / 64, 256, 0, stream>>>(x, cb, bestidx, out);
  vq_final<<<1, 1, 0, stream>>>(accum, out);
}

// Round 6
// 211.725 us; speedup vs baseline: 7.2978x; 1.0485x over previous
//
#include <hip/hip_runtime.h>

#define MTOT 32768
#define KC   4096
#define DDIM 256
#define BM   64           // rows per block, phase 1
#define TKC  64           // codes per LDS tile
#define ZELEMS (MTOT * DDIM)
#define THRESH 2.0e-4f
#define WLCAP 8192
#define RGRID 2048        // rescore grid

typedef _Float16 half8 __attribute__((ext_vector_type(8)));
typedef float f32x4 __attribute__((ext_vector_type(4)));

__device__ __forceinline__ void gload_lds16(const void* g, void* l) {
  __builtin_amdgcn_global_load_lds(
      (const __attribute__((address_space(1))) void*)g,
      (__attribute__((address_space(3))) void*)l, 16, 0, 0);
}

// ---------- np-bit-exact helpers (verified rounds 2-5: absmax 0) ----------
__device__ __forceinline__ float sqr_rn(float v) { return __fmul_rn(v, v); }

__device__ __forceinline__ float np_sumsq_256(const float* p) {
  float half_[2];
#pragma unroll
  for (int h = 0; h < 2; ++h) {
    const float* q = p + h * 128;
    float r[8];
#pragma unroll
    for (int j = 0; j < 8; ++j) r[j] = sqr_rn(q[j]);
#pragma unroll
    for (int i = 8; i < 128; i += 8)
#pragma unroll
      for (int j = 0; j < 8; ++j) r[j] = __fadd_rn(r[j], sqr_rn(q[i + j]));
    half_[h] = __fadd_rn(__fadd_rn(__fadd_rn(r[0], r[1]), __fadd_rn(r[2], r[3])),
                         __fadd_rn(__fadd_rn(r[4], r[5]), __fadd_rn(r[6], r[7])));
  }
  return __fadd_rn(half_[0], half_[1]);
}

// ---------------- prep: S (np-exact), cnorm (np-exact), zero scalars ----------------
__global__ __launch_bounds__(256) void vq_prep(const float* __restrict__ x,
                                               const float* __restrict__ cb,
                                               float* __restrict__ S,
                                               float* __restrict__ cnorm,
                                               int* __restrict__ wl_count,
                                               double* __restrict__ accum) {
  int n = blockIdx.x * 256 + threadIdx.x;
  if (n == 0) { *accum = 0.0; *wl_count = 0; }
  if (n < MTOT) {
    S[n] = np_sumsq_256(x + (size_t)n * DDIM);
  } else {
    int k = n - MTOT;
    if (k < KC) cnorm[k] = np_sumsq_256(cb + (size_t)k * DDIM);
  }
}

// ---------------- cvt: codebook -> f16 x256, pre-swizzled for linear LDS load ----
__global__ __launch_bounds__(256) void vq_cvt(const float* __restrict__ cb,
                                              _Float16* __restrict__ cbsw) {
  int k = blockIdx.x * 256 + threadIdx.x;    // code id 0..4095
  const float* src = cb + (size_t)k * DDIM;
  _Float16* dst = cbsw + (size_t)k * DDIM;
  int sw = k & 7;
#pragma unroll 4
  for (int j = 0; j < 32; ++j) {
    float4 a4 = *reinterpret_cast<const float4*>(src + j * 8);
    float4 b4 = *reinterpret_cast<const float4*>(src + j * 8 + 4);
    union { half8 v; _Float16 h[8]; } u;
    u.h[0] = (_Float16)(a4.x * 256.0f); u.h[1] = (_Float16)(a4.y * 256.0f);
    u.h[2] = (_Float16)(a4.z * 256.0f); u.h[3] = (_Float16)(a4.w * 256.0f);
    u.h[4] = (_Float16)(b4.x * 256.0f); u.h[5] = (_Float16)(b4.y * 256.0f);
    u.h[6] = (_Float16)(b4.z * 256.0f); u.h[7] = (_Float16)(b4.w * 256.0f);
    *reinterpret_cast<half8*>(dst + ((j ^ sw) * 8)) = u.v;
  }
}

// ---------------- phase 1: f16 MFMA surrogate + min1/min2/argmin ----------------
// 256 thr = 4 waves (one code-quarter each), BM=64 rows, 4 A-sets per wave.
// No x LDS tile -> LDS ~69 KB -> 2 independent blocks/CU (destaggered barriers).
__global__ __launch_bounds__(256, 2) void vq_score(const float* __restrict__ x,
                                                   const _Float16* __restrict__ cbsw,
                                                   const float* __restrict__ Sarr,
                                                   const float* __restrict__ cnorm,
                                                   int* __restrict__ bestidx,
                                                   int* __restrict__ wl,
                                                   int* __restrict__ wl_count,
                                                   double* __restrict__ accum) {
  __shared__ _Float16 cbt[2][TKC * DDIM];   // 2 x 32 KB swizzled f16 code tiles
  __shared__ float scrV1[4][BM];            // per-cg candidates
  __shared__ float scrV2[4][BM];
  __shared__ int   scrI1[4][BM];

  const int t = threadIdx.x;
  const int m0 = blockIdx.x * BM;
  const int lane = t & 63, w = t >> 6;      // w = code-quarter (cg)
  const int lo = lane & 15, hi = lane >> 4;

  // ---- issue async load of code tile 0 (pre-swizzled source, linear LDS dest) ----
#pragma unroll
  for (int j = 0; j < 8; ++j)
    gload_lds16(cbsw + j * 2048 + w * 512 + lane * 8,
                &cbt[0][j * 2048 + w * 512]);

  // ---- A fragments straight from global into registers (f16 cvt, same rounding) ----
  half8 a[4][8];
#pragma unroll
  for (int s2 = 0; s2 < 4; ++s2) {
    const float* xr = x + (size_t)(m0 + s2 * 16 + lo) * DDIM + hi * 8;
#pragma unroll
    for (int s = 0; s < 8; ++s) {
      float4 u0 = *reinterpret_cast<const float4*>(xr + s * 32);
      float4 u1 = *reinterpret_cast<const float4*>(xr + s * 32 + 4);
      union { half8 v; _Float16 h[8]; } uu;
      uu.h[0] = (_Float16)u0.x; uu.h[1] = (_Float16)u0.y;
      uu.h[2] = (_Float16)u0.z; uu.h[3] = (_Float16)u0.w;
      uu.h[4] = (_Float16)u1.x; uu.h[5] = (_Float16)u1.y;
      uu.h[6] = (_Float16)u1.z; uu.h[7] = (_Float16)u1.w;
      a[s2][s] = uu.v;
    }
  }
  __syncthreads();   // tile 0 staged (barrier drains vmcnt)

  const int code_l = w * 16 + lo;           // code within tile
  const int bswz = (lo & 7) << 3;

  float v1[4][4], v2[4][4]; int i1[4][4];
#pragma unroll
  for (int s2 = 0; s2 < 4; ++s2)
#pragma unroll
    for (int r = 0; r < 4; ++r) { v1[s2][r] = 3.4e38f; v2[s2][r] = 3.4e38f; i1[s2][r] = 0; }

  for (int kt = 0; kt < KC / TKC; ++kt) {
    const int cur = kt & 1;
    if (kt < KC / TKC - 1) {
#pragma unroll
      for (int j = 0; j < 8; ++j)
        gload_lds16(cbsw + (size_t)(kt + 1) * 16384 + j * 2048 + w * 512 + lane * 8,
                    &cbt[cur ^ 1][j * 2048 + w * 512]);
    }
    const int ktb = kt * TKC;
    const float C = cnorm[ktb + code_l];
    f32x4 acc[4];
#pragma unroll
    for (int s2 = 0; s2 < 4; ++s2) acc[s2] = (f32x4){0.f, 0.f, 0.f, 0.f};
#pragma unroll
    for (int s = 0; s < 8; ++s) {
      half8 b = *reinterpret_cast<half8*>(
          &cbt[cur][(code_l * DDIM + s * 32 + hi * 8) ^ bswz]);
      acc[0] = __builtin_amdgcn_mfma_f32_16x16x32_f16(a[0][s], b, acc[0], 0, 0, 0);
      acc[1] = __builtin_amdgcn_mfma_f32_16x16x32_f16(a[1][s], b, acc[1], 0, 0, 0);
      acc[2] = __builtin_amdgcn_mfma_f32_16x16x32_f16(a[2][s], b, acc[2], 0, 0, 0);
      acc[3] = __builtin_amdgcn_mfma_f32_16x16x32_f16(a[3][s], b, acc[3], 0, 0, 0);
    }
    const int code = ktb + code_l;
#pragma unroll
    for (int s2 = 0; s2 < 4; ++s2) {
#pragma unroll
      for (int r = 0; r < 4; ++r) {
        // s = C - 2E ; acc = 256*E  ->  s = fma(acc, -1/128, C)
        float sv = fmaf(acc[s2][r], -0.0078125f, C);
        bool lt = sv < v1[s2][r];
        v2[s2][r] = fminf(v2[s2][r], lt ? v1[s2][r] : sv);
        if (lt) { v1[s2][r] = sv; i1[s2][r] = code; }
      }
    }
    __syncthreads();   // drains next-tile gloads + protects cbt[cur^1]
  }

  // ---- per-wave reduce across the 16 lo-lanes sharing each row ----
#pragma unroll
  for (int s2 = 0; s2 < 4; ++s2) {
#pragma unroll
    for (int r = 0; r < 4; ++r) {
      float v = v1[s2][r], u = v2[s2][r]; int ii = i1[s2][r];
#pragma unroll
      for (int m = 1; m <= 8; m <<= 1) {
        float ov = __shfl_xor(v, m, 64);
        int   oi = __shfl_xor(ii, m, 64);
        float ou = __shfl_xor(u, m, 64);
        float mx = fmaxf(v, ov);
        u = fminf(fminf(u, ou), mx);
        bool take = (ov < v) || (ov == v && oi < ii);
        if (take) { v = ov; ii = oi; }
      }
      if (lo == 0) {
        int rowl = s2 * 16 + hi * 4 + r;
        scrV1[w][rowl] = v;
        scrV2[w][rowl] = u;
        scrI1[w][rowl] = ii;
      }
    }
  }
  __syncthreads();

  // ---- combine the 4 code-quarter candidates per row (threads 0..63 = wave 0) ----
  float part = 0.f;
  if (t < BM) {
    float bv1 = 3.4e38f, bv2 = 3.4e38f; int bi1 = 0x7fffffff;
#pragma unroll
    for (int c = 0; c < 4; ++c) {
      float v = scrV1[c][t];
      float u = scrV2[c][t];
      int  ii = scrI1[c][t];
      float mx = fmaxf(bv1, v);
      bv2 = fminf(fminf(bv2, u), mx);
      if (v < bv1 || (v == bv1 && ii < bi1)) { bv1 = v; bi1 = ii; }
    }
    int row = m0 + t;
    bestidx[row] = bi1;
    float gap = bv2 - bv1;
    if (gap <= THRESH) {
      int pos = atomicAdd(wl_count, 1);
      if (pos >= WLCAP) part = __fadd_rn(Sarr[row], bv1);   // overflow fallback
      else wl[pos] = row;
    } else {
      part = __fadd_rn(Sarr[row], bv1);    // safe rows: approx D_min to loss
    }
  }
#pragma unroll
  for (int off = 32; off >= 1; off >>= 1) part += __shfl_down(part, off, 64);
  if (t == 0) atomicAdd(accum, (double)part);
}

// ---------------- phase 2: np-bit-exact rescore ----------------
// Work item = (group of 4 rows) x (256-code chunk). Thread = 1 code x 4 rows.
// Codes read straight from global (cb is L2-resident; lines consumed across dq).
__global__ __launch_bounds__(256) void vq_rescore(const float* __restrict__ x,
                                                  const float* __restrict__ cb,
                                                  const float* __restrict__ Sarr,
                                                  const float* __restrict__ cnorm,
                                                  const int* __restrict__ wl,
                                                  const int* __restrict__ wl_count,
                                                  float* __restrict__ pD,
                                                  int* __restrict__ pI) {
  const int cnt = min(*wl_count, WLCAP);
  if (cnt == 0) return;
  const int ngroups = (cnt + 3) >> 2;
  const int nitems = ngroups * 16;

  __shared__ float xs[4][260];
  __shared__ int rsh[4];
  __shared__ float scrv[4][4];
  __shared__ int   scri[4][4];

  const int t = threadIdx.x;
  const int lane = t & 63, w = t >> 6;

  for (int item = blockIdx.x; item < nitems; item += RGRID) {
    const int g = item >> 4, chunk = item & 15;
    __syncthreads();   // protect xs/rsh from previous iteration readers
    if (t < 4) { int e = g * 4 + t; rsh[t] = wl[(e < cnt) ? e : g * 4]; }
    __syncthreads();
    { int i = t >> 6, dq = t & 63;
      *reinterpret_cast<float4*>(&xs[i][dq * 4]) =
          *reinterpret_cast<const float4*>(x + (size_t)rsh[i] * DDIM + dq * 4); }
    __syncthreads();

    const int code = chunk * 256 + t;
    const float* cp = cb + (size_t)code * DDIM;
    const float C = cnorm[code];

    // np einsum order per (row,code): 4 lane accumulators, ascending d, mul-then-add
    float acc[4][4];
#pragma unroll
    for (int i = 0; i < 4; ++i)
#pragma unroll
      for (int l = 0; l < 4; ++l) acc[i][l] = 0.f;

#pragma unroll 8
    for (int dq = 0; dq < 64; ++dq) {
      float4 cv = *reinterpret_cast<const float4*>(cp + dq * 4);
#pragma unroll
      for (int i = 0; i < 4; ++i) {
        float4 xv = *reinterpret_cast<float4*>(&xs[i][dq * 4]);
        acc[i][0] = __fadd_rn(acc[i][0], __fmul_rn(xv.x, cv.x));
        acc[i][1] = __fadd_rn(acc[i][1], __fmul_rn(xv.y, cv.y));
        acc[i][2] = __fadd_rn(acc[i][2], __fmul_rn(xv.z, cv.z));
        acc[i][3] = __fadd_rn(acc[i][3], __fmul_rn(xv.w, cv.w));
      }
    }

    // fold to D per row, then lexicographic block-reduce over the 256 codes
#pragma unroll
    for (int i = 0; i < 4; ++i) {
      float e = __fadd_rn(__fadd_rn(acc[i][0], acc[i][1]),
                          __fadd_rn(acc[i][2], acc[i][3]));
      float Sv = Sarr[rsh[i]];
      float D = __fadd_rn(__fsub_rn(Sv, __fmul_rn(2.0f, e)), C);
      float v = D; int ii = code;
#pragma unroll
      for (int m = 1; m <= 32; m <<= 1) {
        float ov = __shfl_xor(v, m, 64);
        int   oi = __shfl_xor(ii, m, 64);
        if (ov < v || (ov == v && oi < ii)) { v = ov; ii = oi; }
      }
      if (lane == 0) { scrv[i][w] = v; scri[i][w] = ii; }
    }
    __syncthreads();
    if (t < 4) {
      float bv = 3.4e38f; int bi = 0x7fffffff;
#pragma unroll
      for (int c = 0; c < 4; ++c) {
        float v = scrv[t][c]; int ii = scri[t][c];
        if (v < bv || (v == bv && ii < bi)) { bv = v; bi = ii; }
      }
      int rpos = g * 4 + t;
      if (rpos < cnt) { pD[rpos * 16 + chunk] = bv; pI[rpos * 16 + chunk] = bi; }
    }
  }
}

// ---------------- combine chunk partials: lexicographic min over 16 ----------------
__global__ __launch_bounds__(256) void vq_combine(const int* __restrict__ wl,
                                                  const int* __restrict__ wl_count,
                                                  const float* __restrict__ pD,
                                                  const int* __restrict__ pI,
                                                  int* __restrict__ bestidx,
                                                  double* __restrict__ accum) {
  const int cnt = min(*wl_count, WLCAP);
  for (int r = blockIdx.x * 256 + threadIdx.x; r < cnt; r += gridDim.x * 256) {
    float bv = 3.4e38f; int bi = 0x7fffffff;
#pragma unroll
    for (int c = 0; c < 16; ++c) {
      float v = pD[r * 16 + c]; int ii = pI[r * 16 + c];
      if (v < bv || (v == bv && ii < bi)) { bv = v; bi = ii; }
    }
    bestidx[wl[r]] = bi;
    atomicAdd(accum, (double)bv);    // exact D_min for rescored rows
  }
}

// ---------------- phase 3: emit z_q_st, indices ----------------
__global__ __launch_bounds__(256) void vq_emit(const float* __restrict__ x,
                                               const float* __restrict__ cb,
                                               const int* __restrict__ bestidx,
                                               float* __restrict__ out) {
  __shared__ int ish[64];
  const int t = threadIdx.x;
  const int m0 = blockIdx.x * 64;
  if (t < 64) {
    int ii = bestidx[m0 + t];
    ish[t] = ii;
    out[(size_t)ZELEMS + 1 + m0 + t] = (float)ii;
  }
  __syncthreads();
#pragma unroll
  for (int i = 0; i < 16; ++i) {
    int fi = t + i * 256;
    int row = fi >> 6, dc = fi & 63;
    int code = ish[row];
    float4 c4 = *reinterpret_cast<const float4*>(cb + (size_t)code * DDIM + dc * 4);
    float4 x4 = *reinterpret_cast<const float4*>(x + (size_t)(m0 + row) * DDIM + dc * 4);
    float4 o;
    o.x = __fadd_rn(x4.x, __fsub_rn(c4.x, x4.x));
    o.y = __fadd_rn(x4.y, __fsub_rn(c4.y, x4.y));
    o.z = __fadd_rn(x4.z, __fsub_rn(c4.z, x4.z));
    o.w = __fadd_rn(x4.w, __fsub_rn(c4.w, x4.w));
    *reinterpret_cast<float4*>(out + (size_t)(m0 + row) * DDIM + dc * 4) = o;
  }
}

// ---------------- final: loss scalar ----------------
__global__ void vq_final(const double* __restrict__ accum, float* __restrict__ out) {
  out[ZELEMS] = (float)(1.25 * accum[0] / (double)ZELEMS);
}

extern "C" void kernel_launch(void* const* d_in, const int* in_sizes, int n_in,
                              void* d_out, int out_size, void* d_ws, size_t ws_size,
                              hipStream_t stream) {
  const float* x  = (const float*)d_in[0];
  const float* cb = (const float*)d_in[1];
  float* out = (float*)d_out;

  char* ws = (char*)d_ws;
  float*     S        = (float*)(ws + 0);           // 128 KB
  float*     cnorm    = (float*)(ws + 131072);      // 16 KB
  int*       bestidx  = (int*)  (ws + 147456);      // 128 KB
  int*       wl       = (int*)  (ws + 278528);      // 32 KB
  int*       wl_count = (int*)  (ws + 311296);
  double*    accum    = (double*)(ws + 311312);
  float*     pD       = (float*)(ws + 315392);      // 512 KB
  int*       pI       = (int*)  (ws + 839680);      // 512 KB
  _Float16*  cbsw     = (_Float16*)(ws + 1363968);  // 2 MB, swizzled f16 codebook

  vq_prep<<<(MTOT + KC) / 256, 256, 0, stream>>>(x, cb, S, cnorm, wl_count, accum);
  vq_cvt<<<KC / 256, 256, 0, stream>>>(cb, cbsw);
  vq_score<<<MTOT / BM, 256, 0, stream>>>(x, cbsw, S, cnorm, bestidx, wl, wl_count, accum);
  vq_rescore<<<RGRID, 256, 0, stream>>>(x, cb, S, cnorm, wl, wl_count, pD, pI);
  vq_combine<<<8, 256, 0, stream>>>(wl, wl_count, pD, pI, bestidx, accum);
  vq_emit<<<MTOT / 64, 256, 0, stream>>>(x, cb, bestidx, out);
  vq_final<<<1, 1, 0, stream>>>(accum, out);
}

// Round 8
// 205.310 us; speedup vs baseline: 7.5258x; 1.0312x over previous
//
#include <hip/hip_runtime.h>

#define MTOT 32768
#define KC   4096
#define DDIM 256
#define BM   64           // rows per block, phase 1
#define ZELEMS (MTOT * DDIM)
#define THRESH 2.0e-4f
#define WLCAP 8192
#define RGRID 2048        // rescore grid

typedef _Float16 half8 __attribute__((ext_vector_type(8)));
typedef float f32x4 __attribute__((ext_vector_type(4)));

__device__ __forceinline__ void gload_lds16(const void* g, void* l) {
  __builtin_amdgcn_global_load_lds(
      (const __attribute__((address_space(1))) void*)g,
      (__attribute__((address_space(3))) void*)l, 16, 0, 0);
}

// ---------- np-bit-exact helpers (verified rounds 2-6: absmax 0) ----------
__device__ __forceinline__ float sqr_rn(float v) { return __fmul_rn(v, v); }

__device__ __forceinline__ float np_sumsq_256(const float* p) {
  float half_[2];
#pragma unroll
  for (int h = 0; h < 2; ++h) {
    const float* q = p + h * 128;
    float r[8];
#pragma unroll
    for (int j = 0; j < 8; ++j) r[j] = sqr_rn(q[j]);
#pragma unroll
    for (int i = 8; i < 128; i += 8)
#pragma unroll
      for (int j = 0; j < 8; ++j) r[j] = __fadd_rn(r[j], sqr_rn(q[i + j]));
    half_[h] = __fadd_rn(__fadd_rn(__fadd_rn(r[0], r[1]), __fadd_rn(r[2], r[3])),
                         __fadd_rn(__fadd_rn(r[4], r[5]), __fadd_rn(r[6], r[7])));
  }
  return __fadd_rn(half_[0], half_[1]);
}

// ---------------- prep: S (np-exact), cnorm (np-exact), zero scalars ----------------
__global__ __launch_bounds__(256) void vq_prep(const float* __restrict__ x,
                                               const float* __restrict__ cb,
                                               float* __restrict__ S,
                                               float* __restrict__ cnorm,
                                               int* __restrict__ wl_count,
                                               double* __restrict__ accum) {
  int n = blockIdx.x * 256 + threadIdx.x;
  if (n == 0) { *accum = 0.0; *wl_count = 0; }
  if (n < MTOT) {
    S[n] = np_sumsq_256(x + (size_t)n * DDIM);
  } else {
    int k = n - MTOT;
    if (k < KC) cnorm[k] = np_sumsq_256(cb + (size_t)k * DDIM);
  }
}

// ---------------- cvt: codebook -> f16 x256, pre-swizzled for linear LDS load ----
__global__ __launch_bounds__(256) void vq_cvt(const float* __restrict__ cb,
                                              _Float16* __restrict__ cbsw) {
  int k = blockIdx.x * 256 + threadIdx.x;    // code id 0..4095
  const float* src = cb + (size_t)k * DDIM;
  _Float16* dst = cbsw + (size_t)k * DDIM;
  int sw = k & 7;
#pragma unroll 4
  for (int j = 0; j < 32; ++j) {
    float4 a4 = *reinterpret_cast<const float4*>(src + j * 8);
    float4 b4 = *reinterpret_cast<const float4*>(src + j * 8 + 4);
    union { half8 v; _Float16 h[8]; } u;
    u.h[0] = (_Float16)(a4.x * 256.0f); u.h[1] = (_Float16)(a4.y * 256.0f);
    u.h[2] = (_Float16)(a4.z * 256.0f); u.h[3] = (_Float16)(a4.w * 256.0f);
    u.h[4] = (_Float16)(b4.x * 256.0f); u.h[5] = (_Float16)(b4.y * 256.0f);
    u.h[6] = (_Float16)(b4.z * 256.0f); u.h[7] = (_Float16)(b4.w * 256.0f);
    *reinterpret_cast<half8*>(dst + ((j ^ sw) * 8)) = u.v;
  }
}

// ---------------- phase 1: f16 MFMA surrogate + min1/min2/argmin ----------------
// 256 thr = 4 waves, each wave owns a PRIVATE 16-code slice per tile in its own
// double-buffered LDS region -> ZERO barriers in the K-loop; per-wave vmcnt sync.
__global__ __launch_bounds__(256, 2) void vq_score(const float* __restrict__ x,
                                                   const _Float16* __restrict__ cbsw,
                                                   const float* __restrict__ Sarr,
                                                   const float* __restrict__ cnorm,
                                                   int* __restrict__ bestidx,
                                                   int* __restrict__ wl,
                                                   int* __restrict__ wl_count,
                                                   double* __restrict__ accum) {
  __shared__ _Float16 cbt[4][2][4096];      // 4 waves x dbuf x 8 KB = 64 KB
  __shared__ float scrV1[4][BM];            // per-wave candidates
  __shared__ float scrV2[4][BM];
  __shared__ int   scrI1[4][BM];

  const int t = threadIdx.x;
  const int m0 = blockIdx.x * BM;
  const int lane = t & 63, w = t >> 6;      // w = code-quarter
  const int lo = lane & 15, hi = lane >> 4;

  // ---- issue async stage of this wave's tile-0 slice (codes w*16..+15) ----
#pragma unroll
  for (int j = 0; j < 8; ++j)
    gload_lds16(cbsw + w * 4096 + j * 512 + lane * 8, &cbt[w][0][j * 512]);

  // ---- A fragments straight from global into registers (f16 cvt) ----
  half8 a[4][8];
#pragma unroll
  for (int s2 = 0; s2 < 4; ++s2) {
    const float* xr = x + (size_t)(m0 + s2 * 16 + lo) * DDIM + hi * 8;
#pragma unroll
    for (int s = 0; s < 8; ++s) {
      float4 u0 = *reinterpret_cast<const float4*>(xr + s * 32);
      float4 u1 = *reinterpret_cast<const float4*>(xr + s * 32 + 4);
      union { half8 v; _Float16 h[8]; } uu;
      uu.h[0] = (_Float16)u0.x; uu.h[1] = (_Float16)u0.y;
      uu.h[2] = (_Float16)u0.z; uu.h[3] = (_Float16)u0.w;
      uu.h[4] = (_Float16)u1.x; uu.h[5] = (_Float16)u1.y;
      uu.h[6] = (_Float16)u1.z; uu.h[7] = (_Float16)u1.w;
      a[s2][s] = uu.v;
    }
  }

  const int code_l = w * 16 + lo;           // code within 64-code tile
  const int bswz = (lo & 7) << 3;           // cvt stored chunk j at j^(code&7)

  float v1[4][4], v2[4][4]; int i1[4][4];
#pragma unroll
  for (int s2 = 0; s2 < 4; ++s2)
#pragma unroll
    for (int r = 0; r < 4; ++r) { v1[s2][r] = 3.4e38f; v2[s2][r] = 3.4e38f; i1[s2][r] = 0; }

  float Ccur = cnorm[code_l];               // software-pipelined C (tile 0)

  for (int kt = 0; kt < KC / 64; ++kt) {
    const int cur = kt & 1;
    // wait: current tile staged (and everything older) -- per-wave, no barrier
    asm volatile("s_waitcnt vmcnt(0) lgkmcnt(0)" ::: "memory");
    if (kt < KC / 64 - 1) {
      // issue next tile's stage into the other buffer
      const _Float16* src = cbsw + (size_t)(kt + 1) * 16384 + w * 4096 + lane * 8;
#pragma unroll
      for (int j = 0; j < 8; ++j)
        gload_lds16(src + j * 512, &cbt[w][cur ^ 1][j * 512]);
    }
    // next tile's C: consumed only after next vmcnt(0), so its wait is free
    float Cnext = (kt < KC / 64 - 1) ? cnorm[(kt + 1) * 64 + code_l] : 0.f;

    f32x4 acc[4];
#pragma unroll
    for (int s2 = 0; s2 < 4; ++s2) acc[s2] = (f32x4){0.f, 0.f, 0.f, 0.f};
#pragma unroll
    for (int s = 0; s < 8; ++s) {
      // XOR must cover the full low-byte offset (s*32 + hi*8), NOT be pre-added
      half8 b = *reinterpret_cast<half8*>(
          &cbt[w][cur][(lo * 256 + s * 32 + hi * 8) ^ bswz]);
      acc[0] = __builtin_amdgcn_mfma_f32_16x16x32_f16(a[0][s], b, acc[0], 0, 0, 0);
      acc[1] = __builtin_amdgcn_mfma_f32_16x16x32_f16(a[1][s], b, acc[1], 0, 0, 0);
      acc[2] = __builtin_amdgcn_mfma_f32_16x16x32_f16(a[2][s], b, acc[2], 0, 0, 0);
      acc[3] = __builtin_amdgcn_mfma_f32_16x16x32_f16(a[3][s], b, acc[3], 0, 0, 0);
    }
    const int code = kt * 64 + code_l;
#pragma unroll
    for (int s2 = 0; s2 < 4; ++s2) {
#pragma unroll
      for (int r = 0; r < 4; ++r) {
        // s = C - 2E ; acc = 256*E  ->  s = fma(acc, -1/128, C)
        float sv = fmaf(acc[s2][r], -0.0078125f, Ccur);
        bool lt = sv < v1[s2][r];
        v2[s2][r] = fminf(v2[s2][r], lt ? v1[s2][r] : sv);
        if (lt) { v1[s2][r] = sv; i1[s2][r] = code; }
      }
    }
    Ccur = Cnext;
  }

  // ---- per-wave reduce across the 16 lo-lanes sharing each row ----
#pragma unroll
  for (int s2 = 0; s2 < 4; ++s2) {
#pragma unroll
    for (int r = 0; r < 4; ++r) {
      float v = v1[s2][r], u = v2[s2][r]; int ii = i1[s2][r];
#pragma unroll
      for (int m = 1; m <= 8; m <<= 1) {
        float ov = __shfl_xor(v, m, 64);
        int   oi = __shfl_xor(ii, m, 64);
        float ou = __shfl_xor(u, m, 64);
        float mx = fmaxf(v, ov);
        u = fminf(fminf(u, ou), mx);
        bool take = (ov < v) || (ov == v && oi < ii);
        if (take) { v = ov; ii = oi; }
      }
      if (lo == 0) {
        int rowl = s2 * 16 + hi * 4 + r;
        scrV1[w][rowl] = v;
        scrV2[w][rowl] = u;
        scrI1[w][rowl] = ii;
      }
    }
  }
  __syncthreads();   // the ONLY cross-wave sync

  // ---- combine the 4 code-quarter candidates per row (threads 0..63) ----
  float part = 0.f;
  if (t < BM) {
    float bv1 = 3.4e38f, bv2 = 3.4e38f; int bi1 = 0x7fffffff;
#pragma unroll
    for (int c = 0; c < 4; ++c) {
      float v = scrV1[c][t];
      float u = scrV2[c][t];
      int  ii = scrI1[c][t];
      float mx = fmaxf(bv1, v);
      bv2 = fminf(fminf(bv2, u), mx);
      if (v < bv1 || (v == bv1 && ii < bi1)) { bv1 = v; bi1 = ii; }
    }
    int row = m0 + t;
    bestidx[row] = bi1;
    float gap = bv2 - bv1;
    if (gap <= THRESH) {
      int pos = atomicAdd(wl_count, 1);
      if (pos >= WLCAP) part = __fadd_rn(Sarr[row], bv1);   // overflow fallback
      else wl[pos] = row;
    } else {
      part = __fadd_rn(Sarr[row], bv1);    // safe rows: approx D_min to loss
    }
  }
#pragma unroll
  for (int off = 32; off >= 1; off >>= 1) part += __shfl_down(part, off, 64);
  if (t == 0) atomicAdd(accum, (double)part);
}

// ---------------- phase 2: np-bit-exact rescore ----------------
// Work item = (group of 4 rows) x (256-code chunk). Thread = 1 code x 4 rows.
__global__ __launch_bounds__(256) void vq_rescore(const float* __restrict__ x,
                                                  const float* __restrict__ cb,
                                                  const float* __restrict__ Sarr,
                                                  const float* __restrict__ cnorm,
                                                  const int* __restrict__ wl,
                                                  const int* __restrict__ wl_count,
                                                  float* __restrict__ pD,
                                                  int* __restrict__ pI) {
  const int cnt = min(*wl_count, WLCAP);
  if (cnt == 0) return;
  const int ngroups = (cnt + 3) >> 2;
  const int nitems = ngroups * 16;

  __shared__ float xs[4][260];
  __shared__ int rsh[4];
  __shared__ float scrv[4][4];
  __shared__ int   scri[4][4];

  const int t = threadIdx.x;
  const int lane = t & 63, w = t >> 6;

  for (int item = blockIdx.x; item < nitems; item += RGRID) {
    const int g = item >> 4, chunk = item & 15;
    __syncthreads();   // protect xs/rsh from previous iteration readers
    if (t < 4) { int e = g * 4 + t; rsh[t] = wl[(e < cnt) ? e : g * 4]; }
    __syncthreads();
    { int i = t >> 6, dq = t & 63;
      *reinterpret_cast<float4*>(&xs[i][dq * 4]) =
          *reinterpret_cast<const float4*>(x + (size_t)rsh[i] * DDIM + dq * 4); }
    __syncthreads();

    const int code = chunk * 256 + t;
    const float* cp = cb + (size_t)code * DDIM;
    const float C = cnorm[code];

    // np einsum order per (row,code): 4 lane accumulators, ascending d, mul-then-add
    float acc[4][4];
#pragma unroll
    for (int i = 0; i < 4; ++i)
#pragma unroll
      for (int l = 0; l < 4; ++l) acc[i][l] = 0.f;

#pragma unroll 8
    for (int dq = 0; dq < 64; ++dq) {
      float4 cv = *reinterpret_cast<const float4*>(cp + dq * 4);
#pragma unroll
      for (int i = 0; i < 4; ++i) {
        float4 xv = *reinterpret_cast<float4*>(&xs[i][dq * 4]);
        acc[i][0] = __fadd_rn(acc[i][0], __fmul_rn(xv.x, cv.x));
        acc[i][1] = __fadd_rn(acc[i][1], __fmul_rn(xv.y, cv.y));
        acc[i][2] = __fadd_rn(acc[i][2], __fmul_rn(xv.z, cv.z));
        acc[i][3] = __fadd_rn(acc[i][3], __fmul_rn(xv.w, cv.w));
      }
    }

    // fold to D per row, then lexicographic block-reduce over the 256 codes
#pragma unroll
    for (int i = 0; i < 4; ++i) {
      float e = __fadd_rn(__fadd_rn(acc[i][0], acc[i][1]),
                          __fadd_rn(acc[i][2], acc[i][3]));
      float Sv = Sarr[rsh[i]];
      float D = __fadd_rn(__fsub_rn(Sv, __fmul_rn(2.0f, e)), C);
      float v = D; int ii = code;
#pragma unroll
      for (int m = 1; m <= 32; m <<= 1) {
        float ov = __shfl_xor(v, m, 64);
        int   oi = __shfl_xor(ii, m, 64);
        if (ov < v || (ov == v && oi < ii)) { v = ov; ii = oi; }
      }
      if (lane == 0) { scrv[i][w] = v; scri[i][w] = ii; }
    }
    __syncthreads();
    if (t < 4) {
      float bv = 3.4e38f; int bi = 0x7fffffff;
#pragma unroll
      for (int c = 0; c < 4; ++c) {
        float v = scrv[t][c]; int ii = scri[t][c];
        if (v < bv || (v == bv && ii < bi)) { bv = v; bi = ii; }
      }
      int rpos = g * 4 + t;
      if (rpos < cnt) { pD[rpos * 16 + chunk] = bv; pI[rpos * 16 + chunk] = bi; }
    }
  }
}

// ---------------- combine chunk partials: lexicographic min over 16 ----------------
__global__ __launch_bounds__(256) void vq_combine(const int* __restrict__ wl,
                                                  const int* __restrict__ wl_count,
                                                  const float* __restrict__ pD,
                                                  const int* __restrict__ pI,
                                                  int* __restrict__ bestidx,
                                                  double* __restrict__ accum) {
  const int cnt = min(*wl_count, WLCAP);
  for (int r = blockIdx.x * 256 + threadIdx.x; r < cnt; r += gridDim.x * 256) {
    float bv = 3.4e38f; int bi = 0x7fffffff;
#pragma unroll
    for (int c = 0; c < 16; ++c) {
      float v = pD[r * 16 + c]; int ii = pI[r * 16 + c];
      if (v < bv || (v == bv && ii < bi)) { bv = v; bi = ii; }
    }
    bestidx[wl[r]] = bi;
    atomicAdd(accum, (double)bv);    // exact D_min for rescored rows
  }
}

// ---------------- phase 3: emit z_q_st, indices ----------------
__global__ __launch_bounds__(256) void vq_emit(const float* __restrict__ x,
                                               const float* __restrict__ cb,
                                               const int* __restrict__ bestidx,
                                               float* __restrict__ out) {
  __shared__ int ish[64];
  const int t = threadIdx.x;
  const int m0 = blockIdx.x * 64;
  if (t < 64) {
    int ii = bestidx[m0 + t];
    ish[t] = ii;
    out[(size_t)ZELEMS + 1 + m0 + t] = (float)ii;
  }
  __syncthreads();
#pragma unroll
  for (int i = 0; i < 16; ++i) {
    int fi = t + i * 256;
    int row = fi >> 6, dc = fi & 63;
    int code = ish[row];
    float4 c4 = *reinterpret_cast<const float4*>(cb + (size_t)code * DDIM + dc * 4);
    float4 x4 = *reinterpret_cast<const float4*>(x + (size_t)(m0 + row) * DDIM + dc * 4);
    float4 o;
    o.x = __fadd_rn(x4.x, __fsub_rn(c4.x, x4.x));
    o.y = __fadd_rn(x4.y, __fsub_rn(c4.y, x4.y));
    o.z = __fadd_rn(x4.z, __fsub_rn(c4.z, x4.z));
    o.w = __fadd_rn(x4.w, __fsub_rn(c4.w, x4.w));
    *reinterpret_cast<float4*>(out + (size_t)(m0 + row) * DDIM + dc * 4) = o;
  }
}

// ---------------- final: loss scalar ----------------
__global__ void vq_final(const double* __restrict__ accum, float* __restrict__ out) {
  out[ZELEMS] = (float)(1.25 * accum[0] / (double)ZELEMS);
}

extern "C" void kernel_launch(void* const* d_in, const int* in_sizes, int n_in,
                              void* d_out, int out_size, void* d_ws, size_t ws_size,
                              hipStream_t stream) {
  const float* x  = (const float*)d_in[0];
  const float* cb = (const float*)d_in[1];
  float* out = (float*)d_out;

  char* ws = (char*)d_ws;
  float*     S        = (float*)(ws + 0);           // 128 KB
  float*     cnorm    = (float*)(ws + 131072);      // 16 KB
  int*       bestidx  = (int*)  (ws + 147456);      // 128 KB
  int*       wl       = (int*)  (ws + 278528);      // 32 KB
  int*       wl_count = (int*)  (ws + 311296);
  double*    accum    = (double*)(ws + 311312);
  float*     pD       = (float*)(ws + 315392);      // 512 KB
  int*       pI       = (int*)  (ws + 839680);      // 512 KB
  _Float16*  cbsw     = (_Float16*)(ws + 1363968);  // 2 MB, swizzled f16 codebook

  vq_prep<<<(MTOT + KC) / 256, 256, 0, stream>>>(x, cb, S, cnorm, wl_count, accum);
  vq_cvt<<<KC / 256, 256, 0, stream>>>(cb, cbsw);
  vq_score<<<MTOT / BM, 256, 0, stream>>>(x, cbsw, S, cnorm, bestidx, wl, wl_count, accum);
  vq_rescore<<<RGRID, 256, 0, stream>>>(x, cb, S, cnorm, wl, wl_count, pD, pI);
  vq_combine<<<8, 256, 0, stream>>>(wl, wl_count, pD, pI, bestidx, accum);
  vq_emit<<<MTOT / 64, 256, 0, stream>>>(x, cb, bestidx, out);
  vq_final<<<1, 1, 0, stream>>>(accum, out);
}

// Round 9
// 187.569 us; speedup vs baseline: 8.2376x; 1.0946x over previous
//
#include <hip/hip_runtime.h>

#define MTOT 32768
#define KC   4096
#define DDIM 256
#define BM   64           // rows per block, phase 1
#define ZELEMS (MTOT * DDIM)
#define THRESH 2.0e-4f
#define WLCAP 8192
#define RGRID 2048        // rescore grid

typedef _Float16 half8 __attribute__((ext_vector_type(8)));
typedef float f32x4 __attribute__((ext_vector_type(4)));

__device__ __forceinline__ void gload_lds16(const void* g, void* l) {
  __builtin_amdgcn_global_load_lds(
      (const __attribute__((address_space(1))) void*)g,
      (__attribute__((address_space(3))) void*)l, 16, 0, 0);
}

// ---------- np-bit-exact helpers (verified rounds 2-8: absmax 0) ----------
__device__ __forceinline__ float sqr_rn(float v) { return __fmul_rn(v, v); }

// ---------------- fused prep+cvt ----------------
// blocks [0,2048): x rows -> S. blocks [2048,2304): codes -> cnorm + cbsw.
// np pairwise sumsq parallelized over 16 lanes/row: lane (h,j) runs chain r[j]
// of half h (ascending i, exact); combine via commutative __fadd_rn tree
// ((r0+r1)+(r2+r3))+((r4+r5)+(r6+r7)), then half0+half1 -- bit-identical.
__global__ __launch_bounds__(256) void vq_prep2(const float* __restrict__ x,
                                                const float* __restrict__ cb,
                                                float* __restrict__ S,
                                                float* __restrict__ cnorm,
                                                _Float16* __restrict__ cbsw,
                                                int* __restrict__ wl_count,
                                                double* __restrict__ accum) {
  const int t = threadIdx.x;
  if (blockIdx.x == 0 && t == 0) { *accum = 0.0; *wl_count = 0; }
  const int sub = t >> 4, lane16 = t & 15;
  const int h = lane16 >> 3, j = lane16 & 7;
  const bool isrow = blockIdx.x < 2048;
  const int idx = (isrow ? blockIdx.x : blockIdx.x - 2048) * 16 + sub;
  const float* p = (isrow ? x + (size_t)idx * DDIM : cb + (size_t)idx * DDIM);

  // chain r[j] of half h: q[h*128 + j + 8i], i ascending (matches np order)
  float r = 0.f;
  const float* q = p + h * 128 + j;
#pragma unroll
  for (int i = 0; i < 16; ++i) r = __fadd_rn(r, sqr_rn(q[i * 8]));
  // combine chains (commutative fadd => lane order irrelevant bitwise)
  r = __fadd_rn(r, __shfl_xor(r, 1, 64));
  r = __fadd_rn(r, __shfl_xor(r, 2, 64));
  r = __fadd_rn(r, __shfl_xor(r, 4, 64));   // each lane: sum of its half
  float sv = __fadd_rn(r, __shfl_xor(r, 8, 64));
  if (lane16 == 0) {
    if (isrow) S[idx] = sv; else cnorm[idx] = sv;
  }

  if (!isrow) {
    // cvt: f16 x256, pre-swizzled chunks (j ^ (code&7)); lane does chunks lane16, lane16+16
    const int sw = idx & 7;
    _Float16* dst = cbsw + (size_t)idx * DDIM;
#pragma unroll
    for (int c = 0; c < 2; ++c) {
      int jj = lane16 + c * 16;
      float4 a4 = *reinterpret_cast<const float4*>(p + jj * 8);
      float4 b4 = *reinterpret_cast<const float4*>(p + jj * 8 + 4);
      union { half8 v; _Float16 hh[8]; } u;
      u.hh[0] = (_Float16)(a4.x * 256.0f); u.hh[1] = (_Float16)(a4.y * 256.0f);
      u.hh[2] = (_Float16)(a4.z * 256.0f); u.hh[3] = (_Float16)(a4.w * 256.0f);
      u.hh[4] = (_Float16)(b4.x * 256.0f); u.hh[5] = (_Float16)(b4.y * 256.0f);
      u.hh[6] = (_Float16)(b4.z * 256.0f); u.hh[7] = (_Float16)(b4.w * 256.0f);
      *reinterpret_cast<half8*>(dst + ((jj ^ sw) * 8)) = u.v;
    }
  }
}

// ---------------- phase 1: f16 MFMA surrogate + min1/min2/argmin ----------------
// 256 thr = 4 waves, private double-buffered LDS slices, zero K-loop barriers.
// A-fragments PINNED in registers via opaque asm (blocks rematerialization).
__global__ __launch_bounds__(256, 2) void vq_score(const float* __restrict__ x,
                                                   const _Float16* __restrict__ cbsw,
                                                   const float* __restrict__ Sarr,
                                                   const float* __restrict__ cnorm,
                                                   int* __restrict__ bestidx,
                                                   int* __restrict__ wl,
                                                   int* __restrict__ wl_count,
                                                   double* __restrict__ accum) {
  __shared__ _Float16 cbt[4][2][4096];      // 4 waves x dbuf x 8 KB = 64 KB
  __shared__ float scrV1[4][BM];
  __shared__ float scrV2[4][BM];
  __shared__ int   scrI1[4][BM];

  const int t = threadIdx.x;
  const int m0 = blockIdx.x * BM;
  const int lane = t & 63, w = t >> 6;      // w = code-quarter
  const int lo = lane & 15, hi = lane >> 4;

  // ---- issue async stage of this wave's tile-0 slice ----
#pragma unroll
  for (int j = 0; j < 8; ++j)
    gload_lds16(cbsw + w * 4096 + j * 512 + lane * 8, &cbt[w][0][j * 512]);

  // ---- A fragments global -> registers (f16 cvt) ----
  half8 a[4][8];
#pragma unroll
  for (int s2 = 0; s2 < 4; ++s2) {
    const float* xr = x + (size_t)(m0 + s2 * 16 + lo) * DDIM + hi * 8;
#pragma unroll
    for (int s = 0; s < 8; ++s) {
      float4 u0 = *reinterpret_cast<const float4*>(xr + s * 32);
      float4 u1 = *reinterpret_cast<const float4*>(xr + s * 32 + 4);
      union { half8 v; _Float16 h[8]; } uu;
      uu.h[0] = (_Float16)u0.x; uu.h[1] = (_Float16)u0.y;
      uu.h[2] = (_Float16)u0.z; uu.h[3] = (_Float16)u0.w;
      uu.h[4] = (_Float16)u1.x; uu.h[5] = (_Float16)u1.y;
      uu.h[6] = (_Float16)u1.z; uu.h[7] = (_Float16)u1.w;
      a[s2][s] = uu.v;
    }
  }
  // ---- PIN: make each fragment the output of an opaque asm so the compiler
  // cannot rematerialize the global loads inside the K-loop (r8: VGPR=116
  // proved a[] was NOT register-resident; budget here is 256 @ 2 waves/SIMD).
#pragma unroll
  for (int s2 = 0; s2 < 4; ++s2)
#pragma unroll
    for (int s = 0; s < 8; ++s)
      asm volatile("" : "+v"(a[s2][s]));

  const int code_l = w * 16 + lo;
  const int bswz = (lo & 7) << 3;

  float v1[4][4], v2[4][4]; int i1[4][4];
#pragma unroll
  for (int s2 = 0; s2 < 4; ++s2)
#pragma unroll
    for (int r = 0; r < 4; ++r) { v1[s2][r] = 3.4e38f; v2[s2][r] = 3.4e38f; i1[s2][r] = 0; }

  float Ccur = cnorm[code_l];

  for (int kt = 0; kt < KC / 64; ++kt) {
    const int cur = kt & 1;
    asm volatile("s_waitcnt vmcnt(0) lgkmcnt(0)" ::: "memory");
    if (kt < KC / 64 - 1) {
      const _Float16* src = cbsw + (size_t)(kt + 1) * 16384 + w * 4096 + lane * 8;
#pragma unroll
      for (int j = 0; j < 8; ++j)
        gload_lds16(src + j * 512, &cbt[w][cur ^ 1][j * 512]);
    }
    float Cnext = (kt < KC / 64 - 1) ? cnorm[(kt + 1) * 64 + code_l] : 0.f;

    f32x4 acc[4];
#pragma unroll
    for (int s2 = 0; s2 < 4; ++s2) acc[s2] = (f32x4){0.f, 0.f, 0.f, 0.f};
#pragma unroll
    for (int s = 0; s < 8; ++s) {
      half8 b = *reinterpret_cast<half8*>(
          &cbt[w][cur][(lo * 256 + s * 32 + hi * 8) ^ bswz]);
      acc[0] = __builtin_amdgcn_mfma_f32_16x16x32_f16(a[0][s], b, acc[0], 0, 0, 0);
      acc[1] = __builtin_amdgcn_mfma_f32_16x16x32_f16(a[1][s], b, acc[1], 0, 0, 0);
      acc[2] = __builtin_amdgcn_mfma_f32_16x16x32_f16(a[2][s], b, acc[2], 0, 0, 0);
      acc[3] = __builtin_amdgcn_mfma_f32_16x16x32_f16(a[3][s], b, acc[3], 0, 0, 0);
    }
    const int code = kt * 64 + code_l;
#pragma unroll
    for (int s2 = 0; s2 < 4; ++s2) {
#pragma unroll
      for (int r = 0; r < 4; ++r) {
        float sv = fmaf(acc[s2][r], -0.0078125f, Ccur);   // s = C - 2E, acc = 256E
        bool lt = sv < v1[s2][r];
        v2[s2][r] = fminf(v2[s2][r], lt ? v1[s2][r] : sv);
        if (lt) { v1[s2][r] = sv; i1[s2][r] = code; }
      }
    }
    Ccur = Cnext;
  }

  // ---- per-wave reduce across the 16 lo-lanes sharing each row ----
#pragma unroll
  for (int s2 = 0; s2 < 4; ++s2) {
#pragma unroll
    for (int r = 0; r < 4; ++r) {
      float v = v1[s2][r], u = v2[s2][r]; int ii = i1[s2][r];
#pragma unroll
      for (int m = 1; m <= 8; m <<= 1) {
        float ov = __shfl_xor(v, m, 64);
        int   oi = __shfl_xor(ii, m, 64);
        float ou = __shfl_xor(u, m, 64);
        float mx = fmaxf(v, ov);
        u = fminf(fminf(u, ou), mx);
        bool take = (ov < v) || (ov == v && oi < ii);
        if (take) { v = ov; ii = oi; }
      }
      if (lo == 0) {
        int rowl = s2 * 16 + hi * 4 + r;
        scrV1[w][rowl] = v;
        scrV2[w][rowl] = u;
        scrI1[w][rowl] = ii;
      }
    }
  }
  __syncthreads();   // the ONLY cross-wave sync

  float part = 0.f;
  if (t < BM) {
    float bv1 = 3.4e38f, bv2 = 3.4e38f; int bi1 = 0x7fffffff;
#pragma unroll
    for (int c = 0; c < 4; ++c) {
      float v = scrV1[c][t];
      float u = scrV2[c][t];
      int  ii = scrI1[c][t];
      float mx = fmaxf(bv1, v);
      bv2 = fminf(fminf(bv2, u), mx);
      if (v < bv1 || (v == bv1 && ii < bi1)) { bv1 = v; bi1 = ii; }
    }
    int row = m0 + t;
    bestidx[row] = bi1;
    float gap = bv2 - bv1;
    if (gap <= THRESH) {
      int pos = atomicAdd(wl_count, 1);
      if (pos >= WLCAP) part = __fadd_rn(Sarr[row], bv1);
      else wl[pos] = row;
    } else {
      part = __fadd_rn(Sarr[row], bv1);
    }
  }
#pragma unroll
  for (int off = 32; off >= 1; off >>= 1) part += __shfl_down(part, off, 64);
  if (t == 0) atomicAdd(accum, (double)part);
}

// ---------------- phase 2: np-bit-exact rescore ----------------
__global__ __launch_bounds__(256) void vq_rescore(const float* __restrict__ x,
                                                  const float* __restrict__ cb,
                                                  const float* __restrict__ Sarr,
                                                  const float* __restrict__ cnorm,
                                                  const int* __restrict__ wl,
                                                  const int* __restrict__ wl_count,
                                                  float* __restrict__ pD,
                                                  int* __restrict__ pI) {
  const int cnt = min(*wl_count, WLCAP);
  if (cnt == 0) return;
  const int ngroups = (cnt + 3) >> 2;
  const int nitems = ngroups * 16;

  __shared__ float xs[4][260];
  __shared__ int rsh[4];
  __shared__ float scrv[4][4];
  __shared__ int   scri[4][4];

  const int t = threadIdx.x;
  const int lane = t & 63, w = t >> 6;

  for (int item = blockIdx.x; item < nitems; item += RGRID) {
    const int g = item >> 4, chunk = item & 15;
    __syncthreads();
    if (t < 4) { int e = g * 4 + t; rsh[t] = wl[(e < cnt) ? e : g * 4]; }
    __syncthreads();
    { int i = t >> 6, dq = t & 63;
      *reinterpret_cast<float4*>(&xs[i][dq * 4]) =
          *reinterpret_cast<const float4*>(x + (size_t)rsh[i] * DDIM + dq * 4); }
    __syncthreads();

    const int code = chunk * 256 + t;
    const float* cp = cb + (size_t)code * DDIM;
    const float C = cnorm[code];

    float acc[4][4];
#pragma unroll
    for (int i = 0; i < 4; ++i)
#pragma unroll
      for (int l = 0; l < 4; ++l) acc[i][l] = 0.f;

#pragma unroll 8
    for (int dq = 0; dq < 64; ++dq) {
      float4 cv = *reinterpret_cast<const float4*>(cp + dq * 4);
#pragma unroll
      for (int i = 0; i < 4; ++i) {
        float4 xv = *reinterpret_cast<float4*>(&xs[i][dq * 4]);
        acc[i][0] = __fadd_rn(acc[i][0], __fmul_rn(xv.x, cv.x));
        acc[i][1] = __fadd_rn(acc[i][1], __fmul_rn(xv.y, cv.y));
        acc[i][2] = __fadd_rn(acc[i][2], __fmul_rn(xv.z, cv.z));
        acc[i][3] = __fadd_rn(acc[i][3], __fmul_rn(xv.w, cv.w));
      }
    }

#pragma unroll
    for (int i = 0; i < 4; ++i) {
      float e = __fadd_rn(__fadd_rn(acc[i][0], acc[i][1]),
                          __fadd_rn(acc[i][2], acc[i][3]));
      float Sv = Sarr[rsh[i]];
      float D = __fadd_rn(__fsub_rn(Sv, __fmul_rn(2.0f, e)), C);
      float v = D; int ii = code;
#pragma unroll
      for (int m = 1; m <= 32; m <<= 1) {
        float ov = __shfl_xor(v, m, 64);
        int   oi = __shfl_xor(ii, m, 64);
        if (ov < v || (ov == v && oi < ii)) { v = ov; ii = oi; }
      }
      if (lane == 0) { scrv[i][w] = v; scri[i][w] = ii; }
    }
    __syncthreads();
    if (t < 4) {
      float bv = 3.4e38f; int bi = 0x7fffffff;
#pragma unroll
      for (int c = 0; c < 4; ++c) {
        float v = scrv[t][c]; int ii = scri[t][c];
        if (v < bv || (v == bv && ii < bi)) { bv = v; bi = ii; }
      }
      int rpos = g * 4 + t;
      if (rpos < cnt) { pD[rpos * 16 + chunk] = bv; pI[rpos * 16 + chunk] = bi; }
    }
  }
}

// ---------------- combine chunk partials ----------------
__global__ __launch_bounds__(256) void vq_combine(const int* __restrict__ wl,
                                                  const int* __restrict__ wl_count,
                                                  const float* __restrict__ pD,
                                                  const int* __restrict__ pI,
                                                  int* __restrict__ bestidx,
                                                  double* __restrict__ accum) {
  const int cnt = min(*wl_count, WLCAP);
  for (int r = blockIdx.x * 256 + threadIdx.x; r < cnt; r += gridDim.x * 256) {
    float bv = 3.4e38f; int bi = 0x7fffffff;
#pragma unroll
    for (int c = 0; c < 16; ++c) {
      float v = pD[r * 16 + c]; int ii = pI[r * 16 + c];
      if (v < bv || (v == bv && ii < bi)) { bv = v; bi = ii; }
    }
    bestidx[wl[r]] = bi;
    atomicAdd(accum, (double)bv);
  }
}

// ---------------- phase 3: emit z_q_st, indices ----------------
__global__ __launch_bounds__(256) void vq_emit(const float* __restrict__ x,
                                               const float* __restrict__ cb,
                                               const int* __restrict__ bestidx,
                                               float* __restrict__ out) {
  __shared__ int ish[64];
  const int t = threadIdx.x;
  const int m0 = blockIdx.x * 64;
  if (t < 64) {
    int ii = bestidx[m0 + t];
    ish[t] = ii;
    out[(size_t)ZELEMS + 1 + m0 + t] = (float)ii;
  }
  __syncthreads();
#pragma unroll
  for (int i = 0; i < 16; ++i) {
    int fi = t + i * 256;
    int row = fi >> 6, dc = fi & 63;
    int code = ish[row];
    float4 c4 = *reinterpret_cast<const float4*>(cb + (size_t)code * DDIM + dc * 4);
    float4 x4 = *reinterpret_cast<const float4*>(x + (size_t)(m0 + row) * DDIM + dc * 4);
    float4 o;
    o.x = __fadd_rn(x4.x, __fsub_rn(c4.x, x4.x));
    o.y = __fadd_rn(x4.y, __fsub_rn(c4.y, x4.y));
    o.z = __fadd_rn(x4.z, __fsub_rn(c4.z, x4.z));
    o.w = __fadd_rn(x4.w, __fsub_rn(c4.w, x4.w));
    *reinterpret_cast<float4*>(out + (size_t)(m0 + row) * DDIM + dc * 4) = o;
  }
}

// ---------------- final: loss scalar ----------------
__global__ void vq_final(const double* __restrict__ accum, float* __restrict__ out) {
  out[ZELEMS] = (float)(1.25 * accum[0] / (double)ZELEMS);
}

extern "C" void kernel_launch(void* const* d_in, const int* in_sizes, int n_in,
                              void* d_out, int out_size, void* d_ws, size_t ws_size,
                              hipStream_t stream) {
  const float* x  = (const float*)d_in[0];
  const float* cb = (const float*)d_in[1];
  float* out = (float*)d_out;

  char* ws = (char*)d_ws;
  float*     S        = (float*)(ws + 0);           // 128 KB
  float*     cnorm    = (float*)(ws + 131072);      // 16 KB
  int*       bestidx  = (int*)  (ws + 147456);      // 128 KB
  int*       wl       = (int*)  (ws + 278528);      // 32 KB
  int*       wl_count = (int*)  (ws + 311296);
  double*    accum    = (double*)(ws + 311312);
  float*     pD       = (float*)(ws + 315392);      // 512 KB
  int*       pI       = (int*)  (ws + 839680);      // 512 KB
  _Float16*  cbsw     = (_Float16*)(ws + 1363968);  // 2 MB, swizzled f16 codebook

  vq_prep2<<<2304, 256, 0, stream>>>(x, cb, S, cnorm, cbsw, wl_count, accum);
  vq_score<<<MTOT / BM, 256, 0, stream>>>(x, cbsw, S, cnorm, bestidx, wl, wl_count, accum);
  vq_rescore<<<RGRID, 256, 0, stream>>>(x, cb, S, cnorm, wl, wl_count, pD, pI);
  vq_combine<<<8, 256, 0, stream>>>(wl, wl_count, pD, pI, bestidx, accum);
  vq_emit<<<MTOT / 64, 256, 0, stream>>>(x, cb, bestidx, out);
  vq_final<<<1, 1, 0, stream>>>(accum, out);
}

// Round 10
// 186.422 us; speedup vs baseline: 8.2883x; 1.0062x over previous
//
#include <hip/hip_runtime.h>

#define MTOT 32768
#define KC   4096
#define DDIM 256
#define BM   64           // rows per block, phase 1
#define ZELEMS (MTOT * DDIM)
#define THRESH 2.0e-4f
#define WLCAP 8192
#define RGRID 2048        // rescore grid

typedef _Float16 half8 __attribute__((ext_vector_type(8)));
typedef float f32x4 __attribute__((ext_vector_type(4)));

__device__ __forceinline__ void gload_lds16(const void* g, void* l) {
  __builtin_amdgcn_global_load_lds(
      (const __attribute__((address_space(1))) void*)g,
      (__attribute__((address_space(3))) void*)l, 16, 0, 0);
}

// ---------- np-bit-exact helpers (verified rounds 2-9: absmax 0) ----------
__device__ __forceinline__ float sqr_rn(float v) { return __fmul_rn(v, v); }

// ---------------- fused prep+cvt (verified round 9) ----------------
__global__ __launch_bounds__(256) void vq_prep2(const float* __restrict__ x,
                                                const float* __restrict__ cb,
                                                float* __restrict__ S,
                                                float* __restrict__ cnorm,
                                                _Float16* __restrict__ cbsw,
                                                int* __restrict__ wl_count,
                                                double* __restrict__ accum) {
  const int t = threadIdx.x;
  if (blockIdx.x == 0 && t == 0) { *accum = 0.0; *wl_count = 0; }
  const int sub = t >> 4, lane16 = t & 15;
  const int h = lane16 >> 3, j = lane16 & 7;
  const bool isrow = blockIdx.x < 2048;
  const int idx = (isrow ? blockIdx.x : blockIdx.x - 2048) * 16 + sub;
  const float* p = (isrow ? x + (size_t)idx * DDIM : cb + (size_t)idx * DDIM);

  float r = 0.f;
  const float* q = p + h * 128 + j;
#pragma unroll
  for (int i = 0; i < 16; ++i) r = __fadd_rn(r, sqr_rn(q[i * 8]));
  r = __fadd_rn(r, __shfl_xor(r, 1, 64));
  r = __fadd_rn(r, __shfl_xor(r, 2, 64));
  r = __fadd_rn(r, __shfl_xor(r, 4, 64));
  float sv = __fadd_rn(r, __shfl_xor(r, 8, 64));
  if (lane16 == 0) {
    if (isrow) S[idx] = sv; else cnorm[idx] = sv;
  }

  if (!isrow) {
    const int sw = idx & 7;
    _Float16* dst = cbsw + (size_t)idx * DDIM;
#pragma unroll
    for (int c = 0; c < 2; ++c) {
      int jj = lane16 + c * 16;
      float4 a4 = *reinterpret_cast<const float4*>(p + jj * 8);
      float4 b4 = *reinterpret_cast<const float4*>(p + jj * 8 + 4);
      union { half8 v; _Float16 hh[8]; } u;
      u.hh[0] = (_Float16)(a4.x * 256.0f); u.hh[1] = (_Float16)(a4.y * 256.0f);
      u.hh[2] = (_Float16)(a4.z * 256.0f); u.hh[3] = (_Float16)(a4.w * 256.0f);
      u.hh[4] = (_Float16)(b4.x * 256.0f); u.hh[5] = (_Float16)(b4.y * 256.0f);
      u.hh[6] = (_Float16)(b4.z * 256.0f); u.hh[7] = (_Float16)(b4.w * 256.0f);
      *reinterpret_cast<half8*>(dst + ((jj ^ sw) * 8)) = u.v;
    }
  }
}

// ---------------- phase 1: f16 MFMA surrogate + min1/min2/argmin ----------------
// 256 thr = 4 waves, private double-buffered LDS slices, zero K-loop barriers.
// A-fragments pinned IN-LOOP: each iteration re-pins via empty volatile asm, so
// the values are loop-carried through the asm -> remat/AGPR-parking illegal.
__global__ __launch_bounds__(256, 2) void vq_score(const float* __restrict__ x,
                                                   const _Float16* __restrict__ cbsw,
                                                   const float* __restrict__ Sarr,
                                                   const float* __restrict__ cnorm,
                                                   int* __restrict__ bestidx,
                                                   int* __restrict__ wl,
                                                   int* __restrict__ wl_count,
                                                   double* __restrict__ accum) {
  __shared__ _Float16 cbt[4][2][4096];      // 4 waves x dbuf x 8 KB = 64 KB
  __shared__ float scrV1[4][BM];
  __shared__ float scrV2[4][BM];
  __shared__ int   scrI1[4][BM];

  const int t = threadIdx.x;
  const int m0 = blockIdx.x * BM;
  const int lane = t & 63, w = t >> 6;      // w = code-quarter
  const int lo = lane & 15, hi = lane >> 4;

  // ---- issue async stage of this wave's tile-0 slice ----
#pragma unroll
  for (int j = 0; j < 8; ++j)
    gload_lds16(cbsw + w * 4096 + j * 512 + lane * 8, &cbt[w][0][j * 512]);

  // ---- A fragments global -> registers (f16 cvt) ----
  half8 a[4][8];
#pragma unroll
  for (int s2 = 0; s2 < 4; ++s2) {
    const float* xr = x + (size_t)(m0 + s2 * 16 + lo) * DDIM + hi * 8;
#pragma unroll
    for (int s = 0; s < 8; ++s) {
      float4 u0 = *reinterpret_cast<const float4*>(xr + s * 32);
      float4 u1 = *reinterpret_cast<const float4*>(xr + s * 32 + 4);
      union { half8 v; _Float16 h[8]; } uu;
      uu.h[0] = (_Float16)u0.x; uu.h[1] = (_Float16)u0.y;
      uu.h[2] = (_Float16)u0.z; uu.h[3] = (_Float16)u0.w;
      uu.h[4] = (_Float16)u1.x; uu.h[5] = (_Float16)u1.y;
      uu.h[6] = (_Float16)u1.z; uu.h[7] = (_Float16)u1.w;
      a[s2][s] = uu.v;
    }
  }

  const int code_l = w * 16 + lo;
  const int bswz = (lo & 7) << 3;

  float v1[4][4], v2[4][4]; int i1[4][4];
#pragma unroll
  for (int s2 = 0; s2 < 4; ++s2)
#pragma unroll
    for (int r = 0; r < 4; ++r) { v1[s2][r] = 3.4e38f; v2[s2][r] = 3.4e38f; i1[s2][r] = 0; }

  float Ccur = cnorm[code_l];

  for (int kt = 0; kt < KC / 64; ++kt) {
    // ---- IN-LOOP PIN: a[][] must be live arch-VGPRs here, every iteration ----
#pragma unroll
    for (int s2 = 0; s2 < 4; ++s2)
#pragma unroll
      for (int s = 0; s < 8; ++s)
        asm volatile("" : "+v"(a[s2][s]));

    const int cur = kt & 1;
    asm volatile("s_waitcnt vmcnt(0) lgkmcnt(0)" ::: "memory");
    if (kt < KC / 64 - 1) {
      const _Float16* src = cbsw + (size_t)(kt + 1) * 16384 + w * 4096 + lane * 8;
#pragma unroll
      for (int j = 0; j < 8; ++j)
        gload_lds16(src + j * 512, &cbt[w][cur ^ 1][j * 512]);
    }
    float Cnext = (kt < KC / 64 - 1) ? cnorm[(kt + 1) * 64 + code_l] : 0.f;

    f32x4 acc[4];
#pragma unroll
    for (int s2 = 0; s2 < 4; ++s2) acc[s2] = (f32x4){0.f, 0.f, 0.f, 0.f};
#pragma unroll
    for (int s = 0; s < 8; ++s) {
      half8 b = *reinterpret_cast<half8*>(
          &cbt[w][cur][(lo * 256 + s * 32 + hi * 8) ^ bswz]);
      acc[0] = __builtin_amdgcn_mfma_f32_16x16x32_f16(a[0][s], b, acc[0], 0, 0, 0);
      acc[1] = __builtin_amdgcn_mfma_f32_16x16x32_f16(a[1][s], b, acc[1], 0, 0, 0);
      acc[2] = __builtin_amdgcn_mfma_f32_16x16x32_f16(a[2][s], b, acc[2], 0, 0, 0);
      acc[3] = __builtin_amdgcn_mfma_f32_16x16x32_f16(a[3][s], b, acc[3], 0, 0, 0);
    }
    const int code = kt * 64 + code_l;
#pragma unroll
    for (int s2 = 0; s2 < 4; ++s2) {
#pragma unroll
      for (int r = 0; r < 4; ++r) {
        float sv = fmaf(acc[s2][r], -0.0078125f, Ccur);   // s = C - 2E, acc = 256E
        bool lt = sv < v1[s2][r];
        v2[s2][r] = fminf(v2[s2][r], lt ? v1[s2][r] : sv);
        if (lt) { v1[s2][r] = sv; i1[s2][r] = code; }
      }
    }
    Ccur = Cnext;
  }

  // ---- per-wave reduce across the 16 lo-lanes sharing each row ----
#pragma unroll
  for (int s2 = 0; s2 < 4; ++s2) {
#pragma unroll
    for (int r = 0; r < 4; ++r) {
      float v = v1[s2][r], u = v2[s2][r]; int ii = i1[s2][r];
#pragma unroll
      for (int m = 1; m <= 8; m <<= 1) {
        float ov = __shfl_xor(v, m, 64);
        int   oi = __shfl_xor(ii, m, 64);
        float ou = __shfl_xor(u, m, 64);
        float mx = fmaxf(v, ov);
        u = fminf(fminf(u, ou), mx);
        bool take = (ov < v) || (ov == v && oi < ii);
        if (take) { v = ov; ii = oi; }
      }
      if (lo == 0) {
        int rowl = s2 * 16 + hi * 4 + r;
        scrV1[w][rowl] = v;
        scrV2[w][rowl] = u;
        scrI1[w][rowl] = ii;
      }
    }
  }
  __syncthreads();   // the ONLY cross-wave sync

  float part = 0.f;
  if (t < BM) {
    float bv1 = 3.4e38f, bv2 = 3.4e38f; int bi1 = 0x7fffffff;
#pragma unroll
    for (int c = 0; c < 4; ++c) {
      float v = scrV1[c][t];
      float u = scrV2[c][t];
      int  ii = scrI1[c][t];
      float mx = fmaxf(bv1, v);
      bv2 = fminf(fminf(bv2, u), mx);
      if (v < bv1 || (v == bv1 && ii < bi1)) { bv1 = v; bi1 = ii; }
    }
    int row = m0 + t;
    bestidx[row] = bi1;
    float gap = bv2 - bv1;
    if (gap <= THRESH) {
      int pos = atomicAdd(wl_count, 1);
      if (pos >= WLCAP) part = __fadd_rn(Sarr[row], bv1);
      else wl[pos] = row;
    } else {
      part = __fadd_rn(Sarr[row], bv1);
    }
  }
#pragma unroll
  for (int off = 32; off >= 1; off >>= 1) part += __shfl_down(part, off, 64);
  if (t == 0) atomicAdd(accum, (double)part);
}

// ---------------- phase 2: np-bit-exact rescore (verified) ----------------
__global__ __launch_bounds__(256) void vq_rescore(const float* __restrict__ x,
                                                  const float* __restrict__ cb,
                                                  const float* __restrict__ Sarr,
                                                  const float* __restrict__ cnorm,
                                                  const int* __restrict__ wl,
                                                  const int* __restrict__ wl_count,
                                                  float* __restrict__ pD,
                                                  int* __restrict__ pI) {
  const int cnt = min(*wl_count, WLCAP);
  if (cnt == 0) return;
  const int ngroups = (cnt + 3) >> 2;
  const int nitems = ngroups * 16;

  __shared__ float xs[4][260];
  __shared__ int rsh[4];
  __shared__ float scrv[4][4];
  __shared__ int   scri[4][4];

  const int t = threadIdx.x;
  const int lane = t & 63, w = t >> 6;

  for (int item = blockIdx.x; item < nitems; item += RGRID) {
    const int g = item >> 4, chunk = item & 15;
    __syncthreads();
    if (t < 4) { int e = g * 4 + t; rsh[t] = wl[(e < cnt) ? e : g * 4]; }
    __syncthreads();
    { int i = t >> 6, dq = t & 63;
      *reinterpret_cast<float4*>(&xs[i][dq * 4]) =
          *reinterpret_cast<const float4*>(x + (size_t)rsh[i] * DDIM + dq * 4); }
    __syncthreads();

    const int code = chunk * 256 + t;
    const float* cp = cb + (size_t)code * DDIM;
    const float C = cnorm[code];

    float acc[4][4];
#pragma unroll
    for (int i = 0; i < 4; ++i)
#pragma unroll
      for (int l = 0; l < 4; ++l) acc[i][l] = 0.f;

#pragma unroll 8
    for (int dq = 0; dq < 64; ++dq) {
      float4 cv = *reinterpret_cast<const float4*>(cp + dq * 4);
#pragma unroll
      for (int i = 0; i < 4; ++i) {
        float4 xv = *reinterpret_cast<float4*>(&xs[i][dq * 4]);
        acc[i][0] = __fadd_rn(acc[i][0], __fmul_rn(xv.x, cv.x));
        acc[i][1] = __fadd_rn(acc[i][1], __fmul_rn(xv.y, cv.y));
        acc[i][2] = __fadd_rn(acc[i][2], __fmul_rn(xv.z, cv.z));
        acc[i][3] = __fadd_rn(acc[i][3], __fmul_rn(xv.w, cv.w));
      }
    }

#pragma unroll
    for (int i = 0; i < 4; ++i) {
      float e = __fadd_rn(__fadd_rn(acc[i][0], acc[i][1]),
                          __fadd_rn(acc[i][2], acc[i][3]));
      float Sv = Sarr[rsh[i]];
      float D = __fadd_rn(__fsub_rn(Sv, __fmul_rn(2.0f, e)), C);
      float v = D; int ii = code;
#pragma unroll
      for (int m = 1; m <= 32; m <<= 1) {
        float ov = __shfl_xor(v, m, 64);
        int   oi = __shfl_xor(ii, m, 64);
        if (ov < v || (ov == v && oi < ii)) { v = ov; ii = oi; }
      }
      if (lane == 0) { scrv[i][w] = v; scri[i][w] = ii; }
    }
    __syncthreads();
    if (t < 4) {
      float bv = 3.4e38f; int bi = 0x7fffffff;
#pragma unroll
      for (int c = 0; c < 4; ++c) {
        float v = scrv[t][c]; int ii = scri[t][c];
        if (v < bv || (v == bv && ii < bi)) { bv = v; bi = ii; }
      }
      int rpos = g * 4 + t;
      if (rpos < cnt) { pD[rpos * 16 + chunk] = bv; pI[rpos * 16 + chunk] = bi; }
    }
  }
}

// ---------------- combine chunk partials ----------------
__global__ __launch_bounds__(256) void vq_combine(const int* __restrict__ wl,
                                                  const int* __restrict__ wl_count,
                                                  const float* __restrict__ pD,
                                                  const int* __restrict__ pI,
                                                  int* __restrict__ bestidx,
                                                  double* __restrict__ accum) {
  const int cnt = min(*wl_count, WLCAP);
  for (int r = blockIdx.x * 256 + threadIdx.x; r < cnt; r += gridDim.x * 256) {
    float bv = 3.4e38f; int bi = 0x7fffffff;
#pragma unroll
    for (int c = 0; c < 16; ++c) {
      float v = pD[r * 16 + c]; int ii = pI[r * 16 + c];
      if (v < bv || (v == bv && ii < bi)) { bv = v; bi = ii; }
    }
    bestidx[wl[r]] = bi;
    atomicAdd(accum, (double)bv);
  }
}

// ---------------- phase 3: emit z_q_st, indices ----------------
__global__ __launch_bounds__(256) void vq_emit(const float* __restrict__ x,
                                               const float* __restrict__ cb,
                                               const int* __restrict__ bestidx,
                                               float* __restrict__ out) {
  __shared__ int ish[64];
  const int t = threadIdx.x;
  const int m0 = blockIdx.x * 64;
  if (t < 64) {
    int ii = bestidx[m0 + t];
    ish[t] = ii;
    out[(size_t)ZELEMS + 1 + m0 + t] = (float)ii;
  }
  __syncthreads();
#pragma unroll
  for (int i = 0; i < 16; ++i) {
    int fi = t + i * 256;
    int row = fi >> 6, dc = fi & 63;
    int code = ish[row];
    float4 c4 = *reinterpret_cast<const float4*>(cb + (size_t)code * DDIM + dc * 4);
    float4 x4 = *reinterpret_cast<const float4*>(x + (size_t)(m0 + row) * DDIM + dc * 4);
    float4 o;
    o.x = __fadd_rn(x4.x, __fsub_rn(c4.x, x4.x));
    o.y = __fadd_rn(x4.y, __fsub_rn(c4.y, x4.y));
    o.z = __fadd_rn(x4.z, __fsub_rn(c4.z, x4.z));
    o.w = __fadd_rn(x4.w, __fsub_rn(c4.w, x4.w));
    *reinterpret_cast<float4*>(out + (size_t)(m0 + row) * DDIM + dc * 4) = o;
  }
}

// ---------------- final: loss scalar ----------------
__global__ void vq_final(const double* __restrict__ accum, float* __restrict__ out) {
  out[ZELEMS] = (float)(1.25 * accum[0] / (double)ZELEMS);
}

extern "C" void kernel_launch(void* const* d_in, const int* in_sizes, int n_in,
                              void* d_out, int out_size, void* d_ws, size_t ws_size,
                              hipStream_t stream) {
  const float* x  = (const float*)d_in[0];
  const float* cb = (const float*)d_in[1];
  float* out = (float*)d_out;

  char* ws = (char*)d_ws;
  float*     S        = (float*)(ws + 0);           // 128 KB
  float*     cnorm    = (float*)(ws + 131072);      // 16 KB
  int*       bestidx  = (int*)  (ws + 147456);      // 128 KB
  int*       wl       = (int*)  (ws + 278528);      // 32 KB
  int*       wl_count = (int*)  (ws + 311296);
  double*    accum    = (double*)(ws + 311312);
  float*     pD       = (float*)(ws + 315392);      // 512 KB
  int*       pI       = (int*)  (ws + 839680);      // 512 KB
  _Float16*  cbsw     = (_Float16*)(ws + 1363968);  // 2 MB, swizzled f16 codebook

  vq_prep2<<<2304, 256, 0, stream>>>(x, cb, S, cnorm, cbsw, wl_count, accum);
  vq_score<<<MTOT / BM, 256, 0, stream>>>(x, cbsw, S, cnorm, bestidx, wl, wl_count, accum);
  vq_rescore<<<RGRID, 256, 0, stream>>>(x, cb, S, cnorm, wl, wl_count, pD, pI);
  vq_combine<<<8, 256, 0, stream>>>(wl, wl_count, pD, pI, bestidx, accum);
  vq_emit<<<MTOT / 64, 256, 0, stream>>>(x, cb, bestidx, out);
  vq_final<<<1, 1, 0, stream>>>(accum, out);
}